// Round 5
// baseline (297.504 us; speedup 1.0000x reference)
//
#include <hip/hip_runtime.h>
#include <math.h>

#define DMODEL 1024
#define NHEAD  16
#define DK     64
#define BB     2
#define LL     2048
#define MTOT   (BB*LL)   // 4096

#define LOG2E      1.4426950408889634f
#define SCQ        (0.125f * LOG2E)    // folded into Q at projection epilogue
#define C2LOG      (0.1f * LOG2E)      // distance coeff in log2 domain
#define SKIP_BOUND (-24.0f)            // skip tile if max log2(P) below this

typedef __bf16 bf16_t;
typedef __bf16 bf16x8 __attribute__((ext_vector_type(8)));
typedef __bf16 bf16x4 __attribute__((ext_vector_type(4)));
typedef float  f32x4  __attribute__((ext_vector_type(4)));

static __device__ __forceinline__ f32x4 mfma16(bf16x8 a, bf16x8 b, f32x4 c) {
    return __builtin_amdgcn_mfma_f32_16x16x32_bf16(a, b, c, 0, 0, 0);
}
static __device__ __forceinline__ float exp2f_fast(float x) {
    return __builtin_amdgcn_exp2f(x);
}
static __device__ __forceinline__ float log2f_fast(float x) {
    return __builtin_amdgcn_logf(x);
}
static __device__ __forceinline__ void gl_lds16(const bf16_t* g, bf16_t* l) {
    __builtin_amdgcn_global_load_lds(
        (const __attribute__((address_space(1))) unsigned int*)g,
        (__attribute__((address_space(3))) unsigned int*)l, 16, 0, 0);
}

// ---------------------------------------------------------------------------
// fused prep: blocks [0,2048): x -> bf16 (+ logd2); blocks [2048,3072):
// W[k][n] f32 -> Wt[n][k] bf16 (transpose + convert), 4 matrices.
// ---------------------------------------------------------------------------
__global__ __launch_bounds__(256) void prep_fused_k(
    const float* __restrict__ x, const float* __restrict__ dr,
    bf16_t* __restrict__ xb, float* __restrict__ logd2,
    const float* __restrict__ Wq, const float* __restrict__ Wk,
    const float* __restrict__ Wv, const float* __restrict__ Wo,
    bf16_t* __restrict__ Wcat, bf16_t* __restrict__ Wot)
{
    __shared__ __align__(16) float Ts[64][68];
    const int bid = blockIdx.x;
    const int tid = threadIdx.x;
    if (bid < 2048) {
        size_t gid = (size_t)bid * 256 + tid;   // 524288 total
        size_t off = gid * 8;
        float4 a = *(const float4*)(x + off);
        float4 c = *(const float4*)(x + off + 4);
        float va[8] = {a.x, a.y, a.z, a.w, c.x, c.y, c.z, c.w};
        bf16x8 o1;
#pragma unroll
        for (int j = 0; j < 8; ++j) o1[j] = (bf16_t)va[j];
        *(bf16x8*)(xb + off) = o1;
        if (gid < MTOT) logd2[gid] = log2f_fast(dr[gid] + 1e-6f);
    } else {
        const int t = bid - 2048;
        const int z = t >> 8;
        const float* W = (z == 0) ? Wq : (z == 1) ? Wk : (z == 2) ? Wv : Wo;
        bf16_t* dst = (z < 3) ? (Wcat + (size_t)z * DMODEL * DMODEL) : Wot;
        const int k0 = (t & 15) * 64, n0 = ((t >> 4) & 15) * 64;
#pragma unroll
        for (int i = 0; i < 4; ++i) {
            int u = tid + 256 * i, r = u >> 4, c4 = (u & 15) * 4;
            *(float4*)&Ts[r][c4] = *(const float4*)(W + (size_t)(k0 + r) * DMODEL + n0 + c4);
        }
        __syncthreads();
#pragma unroll
        for (int i = 0; i < 2; ++i) {
            int u = tid + 256 * i, n = u >> 3, k8 = (u & 7) * 8;
            bf16x8 v;
#pragma unroll
            for (int j = 0; j < 8; ++j) v[j] = (bf16_t)Ts[k8 + j][n];
            *(bf16x8*)(dst + (size_t)(n0 + n) * DMODEL + k0 + k8) = v;
        }
    }
}

// ---------------------------------------------------------------------------
// 128x128 MFMA GEMM, BK=64, global_load_lds + XOR-swizzled LDS.
// mode 0 (N=3072): QKV epilogue (Q prescaled SCQ; V written transposed+scaled)
// (verified structure; the 256^2 8-phase variant regressed — see journal R1)
// ---------------------------------------------------------------------------
__global__ __launch_bounds__(256, 3) void gemm128_k(
    const bf16_t* __restrict__ A, const bf16_t* __restrict__ Bt,
    const float* __restrict__ b0, const float* __restrict__ b1,
    const float* __restrict__ b2, const float* __restrict__ delta,
    float* __restrict__ outf, bf16_t* __restrict__ outQ,
    bf16_t* __restrict__ outK, bf16_t* __restrict__ outVt, int mode)
{
    __shared__ __align__(16) bf16_t Asw[128 * 64];
    __shared__ __align__(16) bf16_t Bsw[128 * 64];
    const int tid = threadIdx.x, lane = tid & 63, w = tid >> 6;
    const int quad = lane >> 4, n16 = lane & 15;
    const int wm = (w & 1) * 64, wn = (w >> 1) * 64;
    const int m0 = blockIdx.y * 128, n0 = blockIdx.x * 128;
    const int srow = lane >> 3;
    const int scb  = (lane & 7) ^ srow;

    f32x4 acc[4][4] = {};

    for (int K0 = 0; K0 < DMODEL; K0 += 64) {
        __syncthreads();
#pragma unroll
        for (int i = 0; i < 4; ++i) {
            int rb = w * 32 + i * 8;
            gl_lds16(A  + (size_t)(m0 + rb + srow) * DMODEL + K0 + scb * 8,
                     &Asw[rb * 64]);
            gl_lds16(Bt + (size_t)(n0 + rb + srow) * DMODEL + K0 + scb * 8,
                     &Bsw[rb * 64]);
        }
        __syncthreads();
#pragma unroll
        for (int kc = 0; kc < 2; ++kc) {
            const int pcb = ((kc * 4 + quad) ^ (n16 & 7)) * 8;
            bf16x8 af[4], bfv[4];
#pragma unroll
            for (int mi = 0; mi < 4; ++mi)
                af[mi] = *(const bf16x8*)&Asw[(wm + mi * 16 + n16) * 64 + pcb];
#pragma unroll
            for (int ni = 0; ni < 4; ++ni)
                bfv[ni] = *(const bf16x8*)&Bsw[(wn + ni * 16 + n16) * 64 + pcb];
#pragma unroll
            for (int mi = 0; mi < 4; ++mi)
#pragma unroll
                for (int ni = 0; ni < 4; ++ni)
                    acc[mi][ni] = mfma16(af[mi], bfv[ni], acc[mi][ni]);
        }
    }

    if (mode == 0) {
        const int region = n0 >> 10;
        if (region == 2) {
#pragma unroll
            for (int mi = 0; mi < 4; ++mi) {
                const int mbase = m0 + wm + mi * 16 + quad * 4;
                const int bidx = mbase >> 11, l = mbase & (LL - 1);
                const f32x4 dm4 = *(const f32x4*)(delta + mbase);
#pragma unroll
                for (int ni = 0; ni < 4; ++ni) {
                    const int nl = (n0 & 1023) + wn + ni * 16 + n16;
                    const int h = nl >> 6, dd = nl & 63;
                    const float bv = b2[nl];
                    bf16x4 pk;
#pragma unroll
                    for (int r = 0; r < 4; ++r)
                        pk[r] = (bf16_t)(acc[mi][ni][r] * dm4[r] + bv);
                    *(bf16x4*)(outVt + ((size_t)(bidx * NHEAD + h) * DK + dd) * LL + l) = pk;
                }
            }
        } else {
            const float* bias = (region == 0) ? b0 : b1;
            bf16_t* dst = (region == 0) ? outQ : outK;
            const float qs = (region == 0) ? SCQ : 1.0f;
#pragma unroll
            for (int mi = 0; mi < 4; ++mi) {
#pragma unroll
                for (int r = 0; r < 4; ++r) {
                    const int m = m0 + wm + mi * 16 + quad * 4 + r;
                    const int bidx = m >> 11, l = m & (LL - 1);
#pragma unroll
                    for (int ni = 0; ni < 4; ++ni) {
                        const int nl = (n0 & 1023) + wn + ni * 16 + n16;
                        const int h = nl >> 6, dd = nl & 63;
                        float v = (acc[mi][ni][r] + bias[nl]) * qs;
                        dst[(((size_t)(bidx * NHEAD + h) * LL) + l) * DK + dd] = (bf16_t)v;
                    }
                }
            }
        }
    } else {
#pragma unroll
        for (int mi = 0; mi < 4; ++mi) {
#pragma unroll
            for (int r = 0; r < 4; ++r) {
                const int m = m0 + wm + mi * 16 + quad * 4 + r;
#pragma unroll
                for (int ni = 0; ni < 4; ++ni) {
                    const int n = n0 + wn + ni * 16 + n16;
                    outf[(size_t)m * DMODEL + n] = acc[mi][ni][r] + b0[n];
                }
            }
        }
    }
}

// ---------------------------------------------------------------------------
// stats, 256 blocks (8 segments x 256 rows per (b,h)).
// ---------------------------------------------------------------------------
__global__ __launch_bounds__(256) void stats_k(
    const bf16_t* __restrict__ Q, const bf16_t* __restrict__ K,
    const float* __restrict__ logd2, float* __restrict__ Qn,
    float* __restrict__ Kn, float* __restrict__ dlb, float* __restrict__ ldx)
{
    __shared__ float qn_s[256], kn_s[256], dg_s[256];
    const int blk = blockIdx.x;
    const int bh = blk >> 3, seg = blk & 7, b = bh >> 4;
    const int tid = threadIdx.x;
    const int row = seg * 256 + tid;
    const size_t base = (size_t)bh * LL * DK;

    float qn2 = 0.f, kn2 = 0.f, dg = 0.f;
#pragma unroll
    for (int j = 0; j < 8; ++j) {
        bf16x8 qv = *(const bf16x8*)(Q + base + (size_t)row * DK + j * 8);
        bf16x8 kv = *(const bf16x8*)(K + base + (size_t)row * DK + j * 8);
#pragma unroll
        for (int e = 0; e < 8; ++e) {
            float fq = (float)qv[e], fk = (float)kv[e];
            qn2 += fq * fq; kn2 += fk * fk; dg += fq * fk;
        }
    }
    qn_s[tid] = qn2;
    kn_s[tid] = kn2;
    dg_s[tid] = dg + logd2[b * LL + row];
    __syncthreads();

    if (tid < 2) {               // 2 q-tiles of 128 rows in this segment
        float mq = 0.f, md = 1e30f;
        for (int r = 0; r < 128; ++r) {
            mq = fmaxf(mq, qn_s[tid * 128 + r]);
            md = fminf(md, dg_s[tid * 128 + r]);
        }
        Qn[bh * 16 + seg * 2 + tid] = sqrtf(mq);
        dlb[bh * 16 + seg * 2 + tid] = md;
    } else if (tid >= 64 && tid < 68) {   // 4 k-tiles of 64 rows
        const int t = tid - 64;
        float mk = 0.f;
        for (int r = 0; r < 64; ++r) mk = fmaxf(mk, kn_s[t * 64 + r]);
        Kn[bh * 32 + seg * 4 + t] = sqrtf(mk);
    } else if (tid >= 128 && tid < 132 && (bh & 15) == 0) {
        const int t = tid - 128;
        float ml = -1e30f;
        for (int r = 0; r < 64; ++r)
            ml = fmaxf(ml, logd2[b * LL + seg * 256 + t * 64 + r]);
        ldx[b * 32 + seg * 4 + t] = ml;
    }
}

// ---------------------------------------------------------------------------
// mlmin[bh][qtile16] = min over 128 q of ml (after flash)
// ---------------------------------------------------------------------------
__global__ __launch_bounds__(256) void mlstat_k(
    const float* __restrict__ mlws, float* __restrict__ mlmin)
{
    __shared__ float s[2048];
    const int tid = threadIdx.x, bh = blockIdx.x;
#pragma unroll
    for (int i = 0; i < 8; ++i)
        s[tid + 256 * i] = mlws[(size_t)bh * LL + tid + 256 * i];
    __syncthreads();
    if (tid < 16) {
        float m = 1e30f;
        for (int r = 0; r < 128; ++r) m = fminf(m, s[tid * 128 + r]);
        mlmin[bh * 16 + tid] = m;
    }
}

// ---------------------------------------------------------------------------
// MFMA flash attention, S^T form, 64 q/block (1024 blocks -> 16 waves/CU),
// sound far-tile skip (stats indexed by 128-q supertile: still sound bounds).
// ---------------------------------------------------------------------------
__global__ __launch_bounds__(256, 4) void attn_flash_mfma_k(
    const bf16_t* __restrict__ Q, const bf16_t* __restrict__ K,
    const bf16_t* __restrict__ Vt, const float* __restrict__ logd2,
    const float* __restrict__ Qn, const float* __restrict__ Kn,
    const float* __restrict__ dlb, const float* __restrict__ ldx,
    bf16_t* __restrict__ ctx, float* __restrict__ mlout)
{
    __shared__ __align__(16) bf16_t Ks[64][72];
    __shared__ __align__(16) bf16_t Vts[64][72];
    __shared__ __align__(16) bf16_t Ps[4][16][72];
    __shared__ float logds[64];

    const int tid = threadIdx.x;
    const int lane = tid & 63, w = tid >> 6;
    const int quad = lane >> 4, n16 = lane & 15;
    const int bh = blockIdx.x, b = bh >> 4, h = bh & 15;
    const int qt = blockIdx.y, q0 = qt * 64;
    const size_t base = (size_t)bh * LL * DK;
    const int q = q0 + w * 16 + n16;

    bf16x8 qa[2];
#pragma unroll
    for (int kc = 0; kc < 2; ++kc)
        qa[kc] = *(const bf16x8*)(Q + base + (size_t)q * DK + kc * 32 + quad * 8);

    // active-tile mask (block-uniform); stats are per 128-q supertile
    unsigned mask = 0;
    {
        const float qn = Qn[bh * 16 + (qt >> 1)], dl = dlb[bh * 16 + (qt >> 1)];
        for (int t = 0; t < 32; ++t) {
            const int kc0 = t * 64;
            const int dmin = (kc0 > q0 + 63) ? (kc0 - (q0 + 63))
                           : ((q0 > kc0 + 63) ? (q0 - (kc0 + 63)) : 0);
            const float bound = qn * Kn[bh * 32 + t] + ldx[b * 32 + t]
                              - C2LOG * (float)dmin - dl;
            if (bound > SKIP_BOUND) mask |= (1u << t);
        }
    }

    const int strow = tid >> 3, stc8 = (tid & 7) * 8;
    bf16x8 kr0, kr1, vr0, vr1;
    float ldr = 0.f;
    auto prefetch = [&](int k0) {
        kr0 = *(const bf16x8*)(K + base + (size_t)(k0 + strow) * DK + stc8);
        kr1 = *(const bf16x8*)(K + base + (size_t)(k0 + 32 + strow) * DK + stc8);
        vr0 = *(const bf16x8*)(Vt + base + (size_t)strow * LL + k0 + stc8);
        vr1 = *(const bf16x8*)(Vt + base + (size_t)(32 + strow) * LL + k0 + stc8);
        if (tid < 64) ldr = logd2[b * LL + k0 + tid];
    };

    float m_c = -1e30f, l_c = 0.f;
    f32x4 o[4] = {};
    const float dfq = (float)(q - quad * 4);

    int t = (int)__builtin_ctz(mask);   // mask != 0 guaranteed (diagonal)
    prefetch(t * 64);
    for (;;) {
        const unsigned rem = (t < 31) ? (mask >> (t + 1)) : 0u;
        const int tn = rem ? (t + 1 + (int)__builtin_ctz(rem)) : -1;
        __syncthreads();
        *(bf16x8*)&Ks[strow][stc8]       = kr0;
        *(bf16x8*)&Ks[32 + strow][stc8]  = kr1;
        *(bf16x8*)&Vts[strow][stc8]      = vr0;
        *(bf16x8*)&Vts[32 + strow][stc8] = vr1;
        if (tid < 64) logds[tid] = ldr;
        __syncthreads();
        if (tn >= 0) prefetch(tn * 64);
        const int k0 = t * 64;

        f32x4 s[4] = {};
#pragma unroll
        for (int kc = 0; kc < 2; ++kc) {
#pragma unroll
            for (int kt = 0; kt < 4; ++kt) {
                bf16x8 kb = *(const bf16x8*)&Ks[kt * 16 + n16][kc * 32 + quad * 8];
                s[kt] = mfma16(kb, qa[kc], s[kt]);
            }
        }
        const float df = dfq - (float)k0;
#pragma unroll
        for (int kt = 0; kt < 4; ++kt) {
            f32x4 ldv = *(const f32x4*)&logds[kt * 16 + quad * 4];
#pragma unroll
            for (int r = 0; r < 4; ++r)
                s[kt][r] += ldv[r] - C2LOG * fabsf(df - (float)(kt * 16 + r));
        }
        f32x4 mx;
#pragma unroll
        for (int r = 0; r < 4; ++r)
            mx[r] = fmaxf(fmaxf(s[0][r], s[1][r]), fmaxf(s[2][r], s[3][r]));
        float rm = fmaxf(fmaxf(mx[0], mx[1]), fmaxf(mx[2], mx[3]));
        rm = fmaxf(rm, __shfl_xor(rm, 16));
        rm = fmaxf(rm, __shfl_xor(rm, 32));
        const float mn = fmaxf(m_c, rm);
        const float alpha = exp2f_fast(m_c - mn);
        if (__any(mn > m_c)) {
#pragma unroll
            for (int dt = 0; dt < 4; ++dt)
#pragma unroll
                for (int r = 0; r < 4; ++r) o[dt][r] *= alpha;
        }
        f32x4 ps = {0.f, 0.f, 0.f, 0.f};
#pragma unroll
        for (int kt = 0; kt < 4; ++kt)
#pragma unroll
            for (int r = 0; r < 4; ++r) {
                float p = exp2f_fast(s[kt][r] - mn);
                s[kt][r] = p;
                ps[r] += p;
            }
        float psum = (ps[0] + ps[1]) + (ps[2] + ps[3]);
        psum += __shfl_xor(psum, 16);
        psum += __shfl_xor(psum, 32);
        l_c = l_c * alpha + psum;
        m_c = mn;
#pragma unroll
        for (int kt = 0; kt < 4; ++kt) {
            bf16x4 pk;
#pragma unroll
            for (int r = 0; r < 4; ++r) pk[r] = (bf16_t)s[kt][r];
            *(bf16x4*)&Ps[w][n16][kt * 16 + quad * 4] = pk;
        }
        __threadfence_block();
#pragma unroll
        for (int kc = 0; kc < 2; ++kc) {
            bf16x8 pa = *(const bf16x8*)&Ps[w][n16][kc * 32 + quad * 8];
#pragma unroll
            for (int dt = 0; dt < 4; ++dt) {
                bf16x8 vb = *(const bf16x8*)&Vts[dt * 16 + n16][kc * 32 + quad * 8];
                o[dt] = mfma16(vb, pa, o[dt]);
            }
        }
        if (tn < 0) break;
        t = tn;
    }
    const float inv = 1.f / l_c;
#pragma unroll
    for (int dt = 0; dt < 4; ++dt) {
        bf16x4 ov;
#pragma unroll
        for (int r = 0; r < 4; ++r) ov[r] = (bf16_t)(o[dt][r] * inv);
        *(bf16x4*)(ctx + ((size_t)b * LL + q) * DMODEL + h * DK +
                   dt * 16 + quad * 4) = ov;
    }
    if (quad == 0)
        mlout[(size_t)bh * LL + q] = m_c + log2f_fast(l_c);
}

// ---------------------------------------------------------------------------
// fused tail. blocks [0,1024): attn.mean(heads) — BARRIER-FREE, no LDS:
// K/Q/ml/logd read direct from global (all L2/L3-resident: K=8MB, per-tile
// 8KB reused by 16 q-blocks). R4 counters showed the staged version was
// latency-bound (Occ 15%, all pipes <1/3, 705K bank conflicts): the per-head
// 2-barrier serial chain was the critical path, not LDS capacity. Guide
// Common-mistake #7 (drop staging when data L2-fits). Mean blocks are
// ordered diagonal-first (heavy blocks dispatch early -> shorter tail).
// blocks [1024,1536): output-projection GEMM (verified gemm_out_k body).
// ---------------------------------------------------------------------------
__global__ __launch_bounds__(256, 3) void tail_fused_k(
    const bf16_t* __restrict__ A, const bf16_t* __restrict__ Bt,
    const float* __restrict__ b0, float* __restrict__ outf,
    const bf16_t* __restrict__ Q, const bf16_t* __restrict__ K,
    const float* __restrict__ logd2, const float* __restrict__ mlws,
    const float* __restrict__ Qn, const float* __restrict__ Kn,
    const float* __restrict__ mlmin, const float* __restrict__ ldx,
    float* __restrict__ outmean)
{
    // LDS used only by the gemm branch: Asw[64*64] (8192 B) + Bsw[128*64]
    // (16384 B) = 24576 B. Mean branch uses none.
    __shared__ __align__(16) char smem[24576];

    const int bid = blockIdx.x;
    const int tid = threadIdx.x;
    const int lane = tid & 63, w = tid >> 6;
    const int quad = lane >> 4, n16 = lane & 15;

    if (bid >= 1024) {
        // ---------------- output projection GEMM (verified gemm_out_k body)
        bf16_t* Asw = (bf16_t*)smem;
        bf16_t* Bsw = (bf16_t*)(smem + 8192);
        const int gb = bid - 1024;
        const int wm = (w & 1) * 32, wn = (w >> 1) * 64;
        const int m0 = (gb >> 3) * 64, n0 = (gb & 7) * 128;
        const int srow = lane >> 3;
        const int scb  = (lane & 7) ^ srow;

        f32x4 acc[2][4] = {};

        for (int K0 = 0; K0 < DMODEL; K0 += 64) {
            __syncthreads();
#pragma unroll
            for (int i = 0; i < 2; ++i) {
                int rb = w * 16 + i * 8;
                gl_lds16(A + (size_t)(m0 + rb + srow) * DMODEL + K0 + scb * 8,
                         &Asw[rb * 64]);
            }
#pragma unroll
            for (int i = 0; i < 4; ++i) {
                int rb = w * 32 + i * 8;
                gl_lds16(Bt + (size_t)(n0 + rb + srow) * DMODEL + K0 + scb * 8,
                         &Bsw[rb * 64]);
            }
            __syncthreads();
#pragma unroll
            for (int kc = 0; kc < 2; ++kc) {
                const int pcb = ((kc * 4 + quad) ^ (n16 & 7)) * 8;
                bf16x8 af[2], bfv[4];
#pragma unroll
                for (int mi = 0; mi < 2; ++mi)
                    af[mi] = *(const bf16x8*)&Asw[(wm + mi * 16 + n16) * 64 + pcb];
#pragma unroll
                for (int ni = 0; ni < 4; ++ni)
                    bfv[ni] = *(const bf16x8*)&Bsw[(wn + ni * 16 + n16) * 64 + pcb];
#pragma unroll
                for (int mi = 0; mi < 2; ++mi)
#pragma unroll
                    for (int ni = 0; ni < 4; ++ni)
                        acc[mi][ni] = mfma16(af[mi], bfv[ni], acc[mi][ni]);
            }
        }
#pragma unroll
        for (int mi = 0; mi < 2; ++mi) {
#pragma unroll
            for (int r = 0; r < 4; ++r) {
                const int m = m0 + wm + mi * 16 + quad * 4 + r;
#pragma unroll
                for (int ni = 0; ni < 4; ++ni) {
                    const int n = n0 + wn + ni * 16 + n16;
                    outf[(size_t)m * DMODEL + n] = acc[mi][ni][r] + b0[n];
                }
            }
        }
        return;
    }

    // ---------------- attn.mean(heads), barrier-free, LDS-free.
    const int q0 = ((bid >> 5) & 15) * 128, b = bid >> 9;

    // diagonal-first k-tile permutation: rank (bid&31) -> ktile, ordered by
    // distance from the diagonal tiles {c, c+1} outward (block-uniform loop).
    int ktile = 0;
    {
        const int c = q0 >> 6;           // first diagonal k-tile (q0/64)
        int want = bid & 31;
        for (int d = 0; d < 32; ++d) {
            int ka = c - d, kb2 = c + 1 + d;
            if (ka >= 0 && ka < 32) {
                if (want == 0) { ktile = ka; break; }
                --want;
            }
            if (kb2 >= 0 && kb2 < 32) {
                if (want == 0) { ktile = kb2; break; }
                --want;
            }
        }
    }
    const int k0 = ktile * 64;
    const int qq[2] = {q0 + w * 32 + n16, q0 + w * 32 + 16 + n16};

    // bias from global logd2 (tiny, L1/L2-broadcast)
    float bias0[2][4][4];
#pragma unroll
    for (int qg = 0; qg < 2; ++qg) {
        const float df = (float)(qq[qg] - k0 - quad * 4);
#pragma unroll
        for (int kt = 0; kt < 4; ++kt) {
            const f32x4 ldv = *(const f32x4*)(logd2 + b * LL + k0 + kt * 16 + quad * 4);
#pragma unroll
            for (int r = 0; r < 4; ++r)
                bias0[qg][kt][r] = ldv[r] - C2LOG * fabsf(df - (float)(kt * 16 + r));
        }
    }

    const int qt = q0 >> 7;
    const int dmin = (k0 > q0 + 127) ? (k0 - (q0 + 127))
                   : ((q0 > k0 + 63) ? (q0 - (k0 + 63)) : 0);
    unsigned hmask = 0;
    {
        const float dterm = ldx[b * 32 + ktile] - C2LOG * (float)dmin;
        for (int h = 0; h < NHEAD; ++h) {
            const int bh = b * 16 + h;
            const float bound = Qn[bh * 16 + qt] * Kn[bh * 32 + ktile] + dterm
                              - mlmin[bh * 16 + qt];
            if (bound > SKIP_BOUND) hmask |= (1u << h);
        }
    }

    f32x4 acc[2][4] = {};

    if (hmask) {
        int h = (int)__builtin_ctz(hmask);
        for (;;) {
            const unsigned rem = (h < 15) ? (hmask >> (h + 1)) : 0u;
            const int hn = rem ? (h + 1 + (int)__builtin_ctz(rem)) : -1;
            const size_t hb = (size_t)(b * NHEAD + h) * LL * DK;

            const float ml0 = mlws[(size_t)(b * NHEAD + h) * LL + qq[0]];
            const float ml1 = mlws[(size_t)(b * NHEAD + h) * LL + qq[1]];

            f32x4 s[2][4] = {};
#pragma unroll
            for (int kc = 0; kc < 2; ++kc) {
                bf16x8 kbf[4];
#pragma unroll
                for (int kt = 0; kt < 4; ++kt)
                    kbf[kt] = *(const bf16x8*)(K + hb +
                              (size_t)(k0 + kt * 16 + n16) * DK + kc * 32 + quad * 8);
                const bf16x8 qc0 = *(const bf16x8*)(Q + hb + (size_t)qq[0] * DK +
                                                    kc * 32 + quad * 8);
                const bf16x8 qc1 = *(const bf16x8*)(Q + hb + (size_t)qq[1] * DK +
                                                    kc * 32 + quad * 8);
#pragma unroll
                for (int kt = 0; kt < 4; ++kt) {
                    s[0][kt] = mfma16(kbf[kt], qc0, s[0][kt]);
                    s[1][kt] = mfma16(kbf[kt], qc1, s[1][kt]);
                }
            }
#pragma unroll
            for (int kt = 0; kt < 4; ++kt) {
#pragma unroll
                for (int r = 0; r < 4; ++r) {
                    acc[0][kt][r] += exp2f_fast(s[0][kt][r] + bias0[0][kt][r] - ml0);
                    acc[1][kt][r] += exp2f_fast(s[1][kt][r] + bias0[1][kt][r] - ml1);
                }
            }
            if (hn < 0) break;
            h = hn;
        }
    }

    const float invH = 1.f / (float)NHEAD;
#pragma unroll
    for (int qg = 0; qg < 2; ++qg)
#pragma unroll
        for (int kt = 0; kt < 4; ++kt) {
            f32x4 ov;
#pragma unroll
            for (int r = 0; r < 4; ++r) ov[r] = acc[qg][kt][r] * invH;
            *(f32x4*)(outmean + ((size_t)b * LL + qq[qg]) * LL + k0 +
                      kt * 16 + quad * 4) = ov;
        }
}

// ---------------------------------------------------------------------------
extern "C" void kernel_launch(void* const* d_in, const int* in_sizes, int n_in,
                              void* d_out, int out_size, void* d_ws, size_t ws_size,
                              hipStream_t stream) {
    const float* x  = (const float*)d_in[0];
    const float* dr = (const float*)d_in[1];
    const float* Wq = (const float*)d_in[2];
    const float* bq = (const float*)d_in[3];
    const float* Wk = (const float*)d_in[4];
    const float* bk = (const float*)d_in[5];
    const float* Wv = (const float*)d_in[6];
    const float* bv = (const float*)d_in[7];
    const float* Wo = (const float*)d_in[8];
    const float* bo = (const float*)d_in[9];
    float* out = (float*)d_out;
    char* ws = (char*)d_ws;
    const size_t MB = 1ull << 20;

    bf16_t* xb   = (bf16_t*)(ws);             // 8 MB; reused as ctx after QKV gemm
    bf16_t* Wcat = (bf16_t*)(ws + 8 * MB);    // 6 MB  [3072][1024]
    bf16_t* Wot  = (bf16_t*)(ws + 14 * MB);   // 2 MB
    bf16_t* Qb   = (bf16_t*)(ws + 16 * MB);   // 8 MB
    bf16_t* Kb   = (bf16_t*)(ws + 24 * MB);   // 8 MB
    bf16_t* Vtb  = (bf16_t*)(ws + 32 * MB);   // 8 MB  [b,h,dk,l]
    float*  logd = (float*)(ws + 40 * MB);    // 16 KB
    float*  mlws = (float*)(ws + 41 * MB);    // 256 KB
    float*  Qns  = (float*)(ws + 42 * MB);            // [32][16]
    float*  Kns  = (float*)(ws + 42 * MB + 4096);     // [32][32]
    float*  dlb  = (float*)(ws + 42 * MB + 12288);    // [32][16]
    float*  ldxp = (float*)(ws + 42 * MB + 16384);    // [2][32]
    float*  mlmn = (float*)(ws + 42 * MB + 20480);    // [32][16]
    bf16_t* ctx  = xb;

    prep_fused_k<<<3072, 256, 0, stream>>>(x, dr, xb, logd,
                                           Wq, Wk, Wv, Wo, Wcat, Wot);

    gemm128_k<<<dim3(24, 32), 256, 0, stream>>>(xb, Wcat, bq, bk, bv, dr,
                                                nullptr, Qb, Kb, Vtb, 0);
    stats_k<<<256, 256, 0, stream>>>(Qb, Kb, logd, Qns, Kns, dlb, ldxp);

    attn_flash_mfma_k<<<dim3(32, 32), 256, 0, stream>>>(Qb, Kb, Vtb, logd,
                                                        Qns, Kns, dlb, ldxp,
                                                        ctx, mlws);
    mlstat_k<<<32, 256, 0, stream>>>(mlws, mlmn);
    tail_fused_k<<<1536, 256, 0, stream>>>(ctx, Wot, bo, out,
                                           Qb, Kb, logd, mlws, Qns, Kns,
                                           mlmn, ldxp,
                                           out + (size_t)MTOT * DMODEL);
}

// Round 6
// 230.459 us; speedup vs baseline: 1.2909x; 1.2909x over previous
//
#include <hip/hip_runtime.h>
#include <math.h>

#define DMODEL 1024
#define NHEAD  16
#define DK     64
#define BB     2
#define LL     2048
#define MTOT   (BB*LL)   // 4096

#define LOG2E      1.4426950408889634f
#define SCQ        (0.125f * LOG2E)    // folded into Q at projection epilogue
#define C2LOG      (0.1f * LOG2E)      // distance coeff in log2 domain
#define SKIP_BOUND (-24.0f)            // skip tile if max log2(P) below this

typedef __bf16 bf16_t;
typedef __bf16 bf16x8 __attribute__((ext_vector_type(8)));
typedef __bf16 bf16x4 __attribute__((ext_vector_type(4)));
typedef float  f32x4  __attribute__((ext_vector_type(4)));

static __device__ __forceinline__ f32x4 mfma16(bf16x8 a, bf16x8 b, f32x4 c) {
    return __builtin_amdgcn_mfma_f32_16x16x32_bf16(a, b, c, 0, 0, 0);
}
static __device__ __forceinline__ float exp2f_fast(float x) {
    return __builtin_amdgcn_exp2f(x);
}
static __device__ __forceinline__ float log2f_fast(float x) {
    return __builtin_amdgcn_logf(x);
}
static __device__ __forceinline__ void gl_lds16(const bf16_t* g, bf16_t* l) {
    __builtin_amdgcn_global_load_lds(
        (const __attribute__((address_space(1))) unsigned int*)g,
        (__attribute__((address_space(3))) unsigned int*)l, 16, 0, 0);
}

// ---------------------------------------------------------------------------
// fused prep: blocks [0,2048): x -> bf16 (+ logd2); blocks [2048,3072):
// W[k][n] f32 -> Wt[n][k] bf16 (transpose + convert), 4 matrices.
// ---------------------------------------------------------------------------
__global__ __launch_bounds__(256) void prep_fused_k(
    const float* __restrict__ x, const float* __restrict__ dr,
    bf16_t* __restrict__ xb, float* __restrict__ logd2,
    const float* __restrict__ Wq, const float* __restrict__ Wk,
    const float* __restrict__ Wv, const float* __restrict__ Wo,
    bf16_t* __restrict__ Wcat, bf16_t* __restrict__ Wot)
{
    __shared__ __align__(16) float Ts[64][68];
    const int bid = blockIdx.x;
    const int tid = threadIdx.x;
    if (bid < 2048) {
        size_t gid = (size_t)bid * 256 + tid;   // 524288 total
        size_t off = gid * 8;
        float4 a = *(const float4*)(x + off);
        float4 c = *(const float4*)(x + off + 4);
        float va[8] = {a.x, a.y, a.z, a.w, c.x, c.y, c.z, c.w};
        bf16x8 o1;
#pragma unroll
        for (int j = 0; j < 8; ++j) o1[j] = (bf16_t)va[j];
        *(bf16x8*)(xb + off) = o1;
        if (gid < MTOT) logd2[gid] = log2f_fast(dr[gid] + 1e-6f);
    } else {
        const int t = bid - 2048;
        const int z = t >> 8;
        const float* W = (z == 0) ? Wq : (z == 1) ? Wk : (z == 2) ? Wv : Wo;
        bf16_t* dst = (z < 3) ? (Wcat + (size_t)z * DMODEL * DMODEL) : Wot;
        const int k0 = (t & 15) * 64, n0 = ((t >> 4) & 15) * 64;
#pragma unroll
        for (int i = 0; i < 4; ++i) {
            int u = tid + 256 * i, r = u >> 4, c4 = (u & 15) * 4;
            *(float4*)&Ts[r][c4] = *(const float4*)(W + (size_t)(k0 + r) * DMODEL + n0 + c4);
        }
        __syncthreads();
#pragma unroll
        for (int i = 0; i < 2; ++i) {
            int u = tid + 256 * i, n = u >> 3, k8 = (u & 7) * 8;
            bf16x8 v;
#pragma unroll
            for (int j = 0; j < 8; ++j) v[j] = (bf16_t)Ts[k8 + j][n];
            *(bf16x8*)(dst + (size_t)(n0 + n) * DMODEL + k0 + k8) = v;
        }
    }
}

// ---------------------------------------------------------------------------
// 128x128 MFMA GEMM, BK=64, global_load_lds + XOR-swizzled LDS.
// mode 0 (N=3072): QKV epilogue. Q/K regions ALSO write fragment-ordered
// copies Qf/Kf ([bh][t16][kc][quad][n16][8]) so the mean kernel can read
// MFMA fragments COALESCED from global (R5 lesson: fragment reads from
// row-layout global are 16-row scattered gathers -> 2.5x regression).
// ---------------------------------------------------------------------------
__global__ __launch_bounds__(256, 3) void gemm128_k(
    const bf16_t* __restrict__ A, const bf16_t* __restrict__ Bt,
    const float* __restrict__ b0, const float* __restrict__ b1,
    const float* __restrict__ b2, const float* __restrict__ delta,
    bf16_t* __restrict__ outQ, bf16_t* __restrict__ outK,
    bf16_t* __restrict__ outVt, bf16_t* __restrict__ outQf,
    bf16_t* __restrict__ outKf)
{
    __shared__ __align__(16) bf16_t Asw[128 * 64];
    __shared__ __align__(16) bf16_t Bsw[128 * 64];
    const int tid = threadIdx.x, lane = tid & 63, w = tid >> 6;
    const int quad = lane >> 4, n16 = lane & 15;
    const int wm = (w & 1) * 64, wn = (w >> 1) * 64;
    const int m0 = blockIdx.y * 128, n0 = blockIdx.x * 128;
    const int srow = lane >> 3;
    const int scb  = (lane & 7) ^ srow;

    f32x4 acc[4][4] = {};

    for (int K0 = 0; K0 < DMODEL; K0 += 64) {
        __syncthreads();
#pragma unroll
        for (int i = 0; i < 4; ++i) {
            int rb = w * 32 + i * 8;
            gl_lds16(A  + (size_t)(m0 + rb + srow) * DMODEL + K0 + scb * 8,
                     &Asw[rb * 64]);
            gl_lds16(Bt + (size_t)(n0 + rb + srow) * DMODEL + K0 + scb * 8,
                     &Bsw[rb * 64]);
        }
        __syncthreads();
#pragma unroll
        for (int kc = 0; kc < 2; ++kc) {
            const int pcb = ((kc * 4 + quad) ^ (n16 & 7)) * 8;
            bf16x8 af[4], bfv[4];
#pragma unroll
            for (int mi = 0; mi < 4; ++mi)
                af[mi] = *(const bf16x8*)&Asw[(wm + mi * 16 + n16) * 64 + pcb];
#pragma unroll
            for (int ni = 0; ni < 4; ++ni)
                bfv[ni] = *(const bf16x8*)&Bsw[(wn + ni * 16 + n16) * 64 + pcb];
#pragma unroll
            for (int mi = 0; mi < 4; ++mi)
#pragma unroll
                for (int ni = 0; ni < 4; ++ni)
                    acc[mi][ni] = mfma16(af[mi], bfv[ni], acc[mi][ni]);
        }
    }

    const int region = n0 >> 10;
    if (region == 2) {
#pragma unroll
        for (int mi = 0; mi < 4; ++mi) {
            const int mbase = m0 + wm + mi * 16 + quad * 4;
            const int bidx = mbase >> 11, l = mbase & (LL - 1);
            const f32x4 dm4 = *(const f32x4*)(delta + mbase);
#pragma unroll
            for (int ni = 0; ni < 4; ++ni) {
                const int nl = (n0 & 1023) + wn + ni * 16 + n16;
                const int h = nl >> 6, dd = nl & 63;
                const float bv = b2[nl];
                bf16x4 pk;
#pragma unroll
                for (int r = 0; r < 4; ++r)
                    pk[r] = (bf16_t)(acc[mi][ni][r] * dm4[r] + bv);
                *(bf16x4*)(outVt + ((size_t)(bidx * NHEAD + h) * DK + dd) * LL + l) = pk;
            }
        }
    } else {
        const float* bias = (region == 0) ? b0 : b1;
        bf16_t* dst = (region == 0) ? outQ : outK;
        bf16_t* fdst = (region == 0) ? outQf : outKf;
        const float qs = (region == 0) ? SCQ : 1.0f;
#pragma unroll
        for (int mi = 0; mi < 4; ++mi) {
#pragma unroll
            for (int r = 0; r < 4; ++r) {
                const int m = m0 + wm + mi * 16 + quad * 4 + r;
                const int bidx = m >> 11, l = m & (LL - 1);
#pragma unroll
                for (int ni = 0; ni < 4; ++ni) {
                    const int nl = (n0 & 1023) + wn + ni * 16 + n16;
                    const int h = nl >> 6, dd = nl & 63;
                    float v = (acc[mi][ni][r] + bias[nl]) * qs;
                    bf16_t bv16 = (bf16_t)v;
                    dst[(((size_t)(bidx * NHEAD + h) * LL) + l) * DK + dd] = bv16;
                    // fragment layout: [bh][t16=l>>4][kc=dd>>5][quad=(dd>>3)&3][n16=l&15][e=dd&7]
                    fdst[(((size_t)(bidx * NHEAD + h) * (LL >> 4) + (l >> 4)) * 8 +
                          (dd >> 5) * 4 + ((dd >> 3) & 3)) * 128 +
                         (l & 15) * 8 + (dd & 7)] = bv16;
                }
            }
        }
    }
}

// ---------------------------------------------------------------------------
// stats, 256 blocks (8 segments x 256 rows per (b,h)).
// ---------------------------------------------------------------------------
__global__ __launch_bounds__(256) void stats_k(
    const bf16_t* __restrict__ Q, const bf16_t* __restrict__ K,
    const float* __restrict__ logd2, float* __restrict__ Qn,
    float* __restrict__ Kn, float* __restrict__ dlb, float* __restrict__ ldx)
{
    __shared__ float qn_s[256], kn_s[256], dg_s[256];
    const int blk = blockIdx.x;
    const int bh = blk >> 3, seg = blk & 7, b = bh >> 4;
    const int tid = threadIdx.x;
    const int row = seg * 256 + tid;
    const size_t base = (size_t)bh * LL * DK;

    float qn2 = 0.f, kn2 = 0.f, dg = 0.f;
#pragma unroll
    for (int j = 0; j < 8; ++j) {
        bf16x8 qv = *(const bf16x8*)(Q + base + (size_t)row * DK + j * 8);
        bf16x8 kv = *(const bf16x8*)(K + base + (size_t)row * DK + j * 8);
#pragma unroll
        for (int e = 0; e < 8; ++e) {
            float fq = (float)qv[e], fk = (float)kv[e];
            qn2 += fq * fq; kn2 += fk * fk; dg += fq * fk;
        }
    }
    qn_s[tid] = qn2;
    kn_s[tid] = kn2;
    dg_s[tid] = dg + logd2[b * LL + row];
    __syncthreads();

    if (tid < 2) {               // 2 q-tiles of 128 rows in this segment
        float mq = 0.f, md = 1e30f;
        for (int r = 0; r < 128; ++r) {
            mq = fmaxf(mq, qn_s[tid * 128 + r]);
            md = fminf(md, dg_s[tid * 128 + r]);
        }
        Qn[bh * 16 + seg * 2 + tid] = sqrtf(mq);
        dlb[bh * 16 + seg * 2 + tid] = md;
    } else if (tid >= 64 && tid < 68) {   // 4 k-tiles of 64 rows
        const int t = tid - 64;
        float mk = 0.f;
        for (int r = 0; r < 64; ++r) mk = fmaxf(mk, kn_s[t * 64 + r]);
        Kn[bh * 32 + seg * 4 + t] = sqrtf(mk);
    } else if (tid >= 128 && tid < 132 && (bh & 15) == 0) {
        const int t = tid - 128;
        float ml = -1e30f;
        for (int r = 0; r < 64; ++r)
            ml = fmaxf(ml, logd2[b * LL + seg * 256 + t * 64 + r]);
        ldx[b * 32 + seg * 4 + t] = ml;
    }
}

// ---------------------------------------------------------------------------
// mlmin[bh][qtile16] = min over 128 q of ml (after flash)
// ---------------------------------------------------------------------------
__global__ __launch_bounds__(256) void mlstat_k(
    const float* __restrict__ mlws, float* __restrict__ mlmin)
{
    __shared__ float s[2048];
    const int tid = threadIdx.x, bh = blockIdx.x;
#pragma unroll
    for (int i = 0; i < 8; ++i)
        s[tid + 256 * i] = mlws[(size_t)bh * LL + tid + 256 * i];
    __syncthreads();
    if (tid < 16) {
        float m = 1e30f;
        for (int r = 0; r < 128; ++r) m = fminf(m, s[tid * 128 + r]);
        mlmin[bh * 16 + tid] = m;
    }
}

// ---------------------------------------------------------------------------
// MFMA flash attention, S^T form, 64 q/block (1024 blocks -> 16 waves/CU),
// sound far-tile skip (stats indexed by 128-q supertile: still sound bounds).
// ---------------------------------------------------------------------------
__global__ __launch_bounds__(256, 4) void attn_flash_mfma_k(
    const bf16_t* __restrict__ Q, const bf16_t* __restrict__ K,
    const bf16_t* __restrict__ Vt, const float* __restrict__ logd2,
    const float* __restrict__ Qn, const float* __restrict__ Kn,
    const float* __restrict__ dlb, const float* __restrict__ ldx,
    bf16_t* __restrict__ ctx, float* __restrict__ mlout)
{
    __shared__ __align__(16) bf16_t Ks[64][72];
    __shared__ __align__(16) bf16_t Vts[64][72];
    __shared__ __align__(16) bf16_t Ps[4][16][72];
    __shared__ float logds[64];

    const int tid = threadIdx.x;
    const int lane = tid & 63, w = tid >> 6;
    const int quad = lane >> 4, n16 = lane & 15;
    const int bh = blockIdx.x, b = bh >> 4, h = bh & 15;
    const int qt = blockIdx.y, q0 = qt * 64;
    const size_t base = (size_t)bh * LL * DK;
    const int q = q0 + w * 16 + n16;

    bf16x8 qa[2];
#pragma unroll
    for (int kc = 0; kc < 2; ++kc)
        qa[kc] = *(const bf16x8*)(Q + base + (size_t)q * DK + kc * 32 + quad * 8);

    // active-tile mask (block-uniform); stats are per 128-q supertile
    unsigned mask = 0;
    {
        const float qn = Qn[bh * 16 + (qt >> 1)], dl = dlb[bh * 16 + (qt >> 1)];
        for (int t = 0; t < 32; ++t) {
            const int kc0 = t * 64;
            const int dmin = (kc0 > q0 + 63) ? (kc0 - (q0 + 63))
                           : ((q0 > kc0 + 63) ? (q0 - (kc0 + 63)) : 0);
            const float bound = qn * Kn[bh * 32 + t] + ldx[b * 32 + t]
                              - C2LOG * (float)dmin - dl;
            if (bound > SKIP_BOUND) mask |= (1u << t);
        }
    }

    const int strow = tid >> 3, stc8 = (tid & 7) * 8;
    bf16x8 kr0, kr1, vr0, vr1;
    float ldr = 0.f;
    auto prefetch = [&](int k0) {
        kr0 = *(const bf16x8*)(K + base + (size_t)(k0 + strow) * DK + stc8);
        kr1 = *(const bf16x8*)(K + base + (size_t)(k0 + 32 + strow) * DK + stc8);
        vr0 = *(const bf16x8*)(Vt + base + (size_t)strow * LL + k0 + stc8);
        vr1 = *(const bf16x8*)(Vt + base + (size_t)(32 + strow) * LL + k0 + stc8);
        if (tid < 64) ldr = logd2[b * LL + k0 + tid];
    };

    float m_c = -1e30f, l_c = 0.f;
    f32x4 o[4] = {};
    const float dfq = (float)(q - quad * 4);

    int t = (int)__builtin_ctz(mask);   // mask != 0 guaranteed (diagonal)
    prefetch(t * 64);
    for (;;) {
        const unsigned rem = (t < 31) ? (mask >> (t + 1)) : 0u;
        const int tn = rem ? (t + 1 + (int)__builtin_ctz(rem)) : -1;
        __syncthreads();
        *(bf16x8*)&Ks[strow][stc8]       = kr0;
        *(bf16x8*)&Ks[32 + strow][stc8]  = kr1;
        *(bf16x8*)&Vts[strow][stc8]      = vr0;
        *(bf16x8*)&Vts[32 + strow][stc8] = vr1;
        if (tid < 64) logds[tid] = ldr;
        __syncthreads();
        if (tn >= 0) prefetch(tn * 64);
        const int k0 = t * 64;

        f32x4 s[4] = {};
#pragma unroll
        for (int kc = 0; kc < 2; ++kc) {
#pragma unroll
            for (int kt = 0; kt < 4; ++kt) {
                bf16x8 kb = *(const bf16x8*)&Ks[kt * 16 + n16][kc * 32 + quad * 8];
                s[kt] = mfma16(kb, qa[kc], s[kt]);
            }
        }
        const float df = dfq - (float)k0;
#pragma unroll
        for (int kt = 0; kt < 4; ++kt) {
            f32x4 ldv = *(const f32x4*)&logds[kt * 16 + quad * 4];
#pragma unroll
            for (int r = 0; r < 4; ++r)
                s[kt][r] += ldv[r] - C2LOG * fabsf(df - (float)(kt * 16 + r));
        }
        f32x4 mx;
#pragma unroll
        for (int r = 0; r < 4; ++r)
            mx[r] = fmaxf(fmaxf(s[0][r], s[1][r]), fmaxf(s[2][r], s[3][r]));
        float rm = fmaxf(fmaxf(mx[0], mx[1]), fmaxf(mx[2], mx[3]));
        rm = fmaxf(rm, __shfl_xor(rm, 16));
        rm = fmaxf(rm, __shfl_xor(rm, 32));
        const float mn = fmaxf(m_c, rm);
        const float alpha = exp2f_fast(m_c - mn);
        if (__any(mn > m_c)) {
#pragma unroll
            for (int dt = 0; dt < 4; ++dt)
#pragma unroll
                for (int r = 0; r < 4; ++r) o[dt][r] *= alpha;
        }
        f32x4 ps = {0.f, 0.f, 0.f, 0.f};
#pragma unroll
        for (int kt = 0; kt < 4; ++kt)
#pragma unroll
            for (int r = 0; r < 4; ++r) {
                float p = exp2f_fast(s[kt][r] - mn);
                s[kt][r] = p;
                ps[r] += p;
            }
        float psum = (ps[0] + ps[1]) + (ps[2] + ps[3]);
        psum += __shfl_xor(psum, 16);
        psum += __shfl_xor(psum, 32);
        l_c = l_c * alpha + psum;
        m_c = mn;
#pragma unroll
        for (int kt = 0; kt < 4; ++kt) {
            bf16x4 pk;
#pragma unroll
            for (int r = 0; r < 4; ++r) pk[r] = (bf16_t)s[kt][r];
            *(bf16x4*)&Ps[w][n16][kt * 16 + quad * 4] = pk;
        }
        __threadfence_block();
#pragma unroll
        for (int kc = 0; kc < 2; ++kc) {
            bf16x8 pa = *(const bf16x8*)&Ps[w][n16][kc * 32 + quad * 8];
#pragma unroll
            for (int dt = 0; dt < 4; ++dt) {
                bf16x8 vb = *(const bf16x8*)&Vts[dt * 16 + n16][kc * 32 + quad * 8];
                o[dt] = mfma16(vb, pa, o[dt]);
            }
        }
        if (tn < 0) break;
        t = tn;
    }
    const float inv = 1.f / l_c;
#pragma unroll
    for (int dt = 0; dt < 4; ++dt) {
        bf16x4 ov;
#pragma unroll
        for (int r = 0; r < 4; ++r) ov[r] = (bf16_t)(o[dt][r] * inv);
        *(bf16x4*)(ctx + ((size_t)b * LL + q) * DMODEL + h * DK +
                   dt * 16 + quad * 4) = ov;
    }
    if (quad == 0)
        mlout[(size_t)bh * LL + q] = m_c + log2f_fast(l_c);
}

// ---------------------------------------------------------------------------
// fused tail. blocks [0,1024): attn.mean(heads) — barrier-free, LDS-free,
// reading Qf/Kf FRAGMENT-ORDERED global copies (coalesced 256-B segments per
// quad-group; fixes R5's scattered-gather regression while keeping the
// barrier-free wave independence that R4's staged loop lacked).
// blocks [1024,1536): output-projection GEMM (verified gemm_out_k body).
// ---------------------------------------------------------------------------
__global__ __launch_bounds__(256, 3) void tail_fused_k(
    const bf16_t* __restrict__ A, const bf16_t* __restrict__ Bt,
    const float* __restrict__ b0, float* __restrict__ outf,
    const bf16_t* __restrict__ Qf, const bf16_t* __restrict__ Kf,
    const float* __restrict__ logd2, const float* __restrict__ mlws,
    const float* __restrict__ Qn, const float* __restrict__ Kn,
    const float* __restrict__ mlmin, const float* __restrict__ ldx,
    float* __restrict__ outmean)
{
    // LDS used only by the gemm branch.
    __shared__ __align__(16) char smem[24576];

    const int bid = blockIdx.x;
    const int tid = threadIdx.x;
    const int lane = tid & 63, w = tid >> 6;
    const int quad = lane >> 4, n16 = lane & 15;

    if (bid >= 1024) {
        // ---------------- output projection GEMM (verified gemm_out_k body)
        bf16_t* Asw = (bf16_t*)smem;
        bf16_t* Bsw = (bf16_t*)(smem + 8192);
        const int gb = bid - 1024;
        const int wm = (w & 1) * 32, wn = (w >> 1) * 64;
        const int m0 = (gb >> 3) * 64, n0 = (gb & 7) * 128;
        const int srow = lane >> 3;
        const int scb  = (lane & 7) ^ srow;

        f32x4 acc[2][4] = {};

        for (int K0 = 0; K0 < DMODEL; K0 += 64) {
            __syncthreads();
#pragma unroll
            for (int i = 0; i < 2; ++i) {
                int rb = w * 16 + i * 8;
                gl_lds16(A + (size_t)(m0 + rb + srow) * DMODEL + K0 + scb * 8,
                         &Asw[rb * 64]);
            }
#pragma unroll
            for (int i = 0; i < 4; ++i) {
                int rb = w * 32 + i * 8;
                gl_lds16(Bt + (size_t)(n0 + rb + srow) * DMODEL + K0 + scb * 8,
                         &Bsw[rb * 64]);
            }
            __syncthreads();
#pragma unroll
            for (int kc = 0; kc < 2; ++kc) {
                const int pcb = ((kc * 4 + quad) ^ (n16 & 7)) * 8;
                bf16x8 af[2], bfv[4];
#pragma unroll
                for (int mi = 0; mi < 2; ++mi)
                    af[mi] = *(const bf16x8*)&Asw[(wm + mi * 16 + n16) * 64 + pcb];
#pragma unroll
                for (int ni = 0; ni < 4; ++ni)
                    bfv[ni] = *(const bf16x8*)&Bsw[(wn + ni * 16 + n16) * 64 + pcb];
#pragma unroll
                for (int mi = 0; mi < 2; ++mi)
#pragma unroll
                    for (int ni = 0; ni < 4; ++ni)
                        acc[mi][ni] = mfma16(af[mi], bfv[ni], acc[mi][ni]);
            }
        }
#pragma unroll
        for (int mi = 0; mi < 2; ++mi) {
#pragma unroll
            for (int r = 0; r < 4; ++r) {
                const int m = m0 + wm + mi * 16 + quad * 4 + r;
#pragma unroll
                for (int ni = 0; ni < 4; ++ni) {
                    const int n = n0 + wn + ni * 16 + n16;
                    outf[(size_t)m * DMODEL + n] = acc[mi][ni][r] + b0[n];
                }
            }
        }
        return;
    }

    // ---------------- attn.mean(heads), barrier-free, LDS-free, coalesced.
    const int q0 = ((bid >> 5) & 15) * 128, b = bid >> 9;

    // diagonal-first k-tile permutation (block-uniform; verified R5).
    int ktile = 0;
    {
        const int c = q0 >> 6;
        int want = bid & 31;
        for (int d = 0; d < 32; ++d) {
            int ka = c - d, kb2 = c + 1 + d;
            if (ka >= 0 && ka < 32) {
                if (want == 0) { ktile = ka; break; }
                --want;
            }
            if (kb2 >= 0 && kb2 < 32) {
                if (want == 0) { ktile = kb2; break; }
                --want;
            }
        }
    }
    const int k0 = ktile * 64;
    const int qq[2] = {q0 + w * 32 + n16, q0 + w * 32 + 16 + n16};

    float bias0[2][4][4];
#pragma unroll
    for (int qg = 0; qg < 2; ++qg) {
        const float df = (float)(qq[qg] - k0 - quad * 4);
#pragma unroll
        for (int kt = 0; kt < 4; ++kt) {
            const f32x4 ldv = *(const f32x4*)(logd2 + b * LL + k0 + kt * 16 + quad * 4);
#pragma unroll
            for (int r = 0; r < 4; ++r)
                bias0[qg][kt][r] = ldv[r] - C2LOG * fabsf(df - (float)(kt * 16 + r));
        }
    }

    const int qt = q0 >> 7;
    const int dmin = (k0 > q0 + 127) ? (k0 - (q0 + 127))
                   : ((q0 > k0 + 63) ? (q0 - (k0 + 63)) : 0);
    unsigned hmask = 0;
    {
        const float dterm = ldx[b * 32 + ktile] - C2LOG * (float)dmin;
        for (int h = 0; h < NHEAD; ++h) {
            const int bh = b * 16 + h;
            const float bound = Qn[bh * 16 + qt] * Kn[bh * 32 + ktile] + dterm
                              - mlmin[bh * 16 + qt];
            if (bound > SKIP_BOUND) hmask |= (1u << h);
        }
    }

    f32x4 acc[2][4] = {};

    if (hmask) {
        const int kt16 = k0 >> 4;             // k-row block base (t16 units)
        const int qt16 = (q0 >> 4) + w * 2;   // this wave's q-row block base
        int h = (int)__builtin_ctz(hmask);
        for (;;) {
            const unsigned rem = (h < 15) ? (hmask >> (h + 1)) : 0u;
            const int hn = rem ? (h + 1 + (int)__builtin_ctz(rem)) : -1;
            const size_t hb = (size_t)(b * NHEAD + h) * LL * DK;  // == frag base

            const float ml0 = mlws[(size_t)(b * NHEAD + h) * LL + qq[0]];
            const float ml1 = mlws[(size_t)(b * NHEAD + h) * LL + qq[1]];

            f32x4 s[2][4] = {};
#pragma unroll
            for (int kc = 0; kc < 2; ++kc) {
                bf16x8 kbf[4];
#pragma unroll
                for (int kt = 0; kt < 4; ++kt)
                    kbf[kt] = *(const bf16x8*)(Kf + hb +
                              ((size_t)(kt16 + kt) * 8 + kc * 4 + quad) * 128 +
                              n16 * 8);
                const bf16x8 qc0 = *(const bf16x8*)(Qf + hb +
                              ((size_t)qt16 * 8 + kc * 4 + quad) * 128 + n16 * 8);
                const bf16x8 qc1 = *(const bf16x8*)(Qf + hb +
                              ((size_t)(qt16 + 1) * 8 + kc * 4 + quad) * 128 + n16 * 8);
#pragma unroll
                for (int kt = 0; kt < 4; ++kt) {
                    s[0][kt] = mfma16(kbf[kt], qc0, s[0][kt]);
                    s[1][kt] = mfma16(kbf[kt], qc1, s[1][kt]);
                }
            }
#pragma unroll
            for (int kt = 0; kt < 4; ++kt) {
#pragma unroll
                for (int r = 0; r < 4; ++r) {
                    acc[0][kt][r] += exp2f_fast(s[0][kt][r] + bias0[0][kt][r] - ml0);
                    acc[1][kt][r] += exp2f_fast(s[1][kt][r] + bias0[1][kt][r] - ml1);
                }
            }
            if (hn < 0) break;
            h = hn;
        }
    }

    const float invH = 1.f / (float)NHEAD;
#pragma unroll
    for (int qg = 0; qg < 2; ++qg)
#pragma unroll
        for (int kt = 0; kt < 4; ++kt) {
            f32x4 ov;
#pragma unroll
            for (int r = 0; r < 4; ++r) ov[r] = acc[qg][kt][r] * invH;
            *(f32x4*)(outmean + ((size_t)b * LL + qq[qg]) * LL + k0 +
                      kt * 16 + quad * 4) = ov;
        }
}

// ---------------------------------------------------------------------------
extern "C" void kernel_launch(void* const* d_in, const int* in_sizes, int n_in,
                              void* d_out, int out_size, void* d_ws, size_t ws_size,
                              hipStream_t stream) {
    const float* x  = (const float*)d_in[0];
    const float* dr = (const float*)d_in[1];
    const float* Wq = (const float*)d_in[2];
    const float* bq = (const float*)d_in[3];
    const float* Wk = (const float*)d_in[4];
    const float* bk = (const float*)d_in[5];
    const float* Wv = (const float*)d_in[6];
    const float* bv = (const float*)d_in[7];
    const float* Wo = (const float*)d_in[8];
    const float* bo = (const float*)d_in[9];
    float* out = (float*)d_out;
    char* ws = (char*)d_ws;
    const size_t MB = 1ull << 20;

    bf16_t* xb   = (bf16_t*)(ws);             // 8 MB; reused as ctx after QKV gemm
    bf16_t* Wcat = (bf16_t*)(ws + 8 * MB);    // 6 MB  [3072][1024]
    bf16_t* Wot  = (bf16_t*)(ws + 14 * MB);   // 2 MB
    bf16_t* Qb   = (bf16_t*)(ws + 16 * MB);   // 8 MB
    bf16_t* Kb   = (bf16_t*)(ws + 24 * MB);   // 8 MB
    bf16_t* Vtb  = (bf16_t*)(ws + 32 * MB);   // 8 MB  [b,h,dk,l]
    float*  logd = (float*)(ws + 40 * MB);    // 16 KB
    float*  mlws = (float*)(ws + 41 * MB);    // 256 KB
    float*  Qns  = (float*)(ws + 42 * MB);            // [32][16]
    float*  Kns  = (float*)(ws + 42 * MB + 4096);     // [32][32]
    float*  dlb  = (float*)(ws + 42 * MB + 12288);    // [32][16]
    float*  ldxp = (float*)(ws + 42 * MB + 16384);    // [2][32]
    float*  mlmn = (float*)(ws + 42 * MB + 20480);    // [32][16]
    bf16_t* Kf   = (bf16_t*)(ws + 43 * MB);   // 8 MB fragment-ordered K
    bf16_t* Qf   = (bf16_t*)(ws + 51 * MB);   // 8 MB fragment-ordered Q
    bf16_t* ctx  = xb;

    prep_fused_k<<<3072, 256, 0, stream>>>(x, dr, xb, logd,
                                           Wq, Wk, Wv, Wo, Wcat, Wot);

    gemm128_k<<<dim3(24, 32), 256, 0, stream>>>(xb, Wcat, bq, bk, bv, dr,
                                                Qb, Kb, Vtb, Qf, Kf);
    stats_k<<<256, 256, 0, stream>>>(Qb, Kb, logd, Qns, Kns, dlb, ldxp);

    attn_flash_mfma_k<<<dim3(32, 32), 256, 0, stream>>>(Qb, Kb, Vtb, logd,
                                                        Qns, Kns, dlb, ldxp,
                                                        ctx, mlws);
    mlstat_k<<<32, 256, 0, stream>>>(mlws, mlmn);
    tail_fused_k<<<1536, 256, 0, stream>>>(ctx, Wot, bo, out,
                                           Qf, Kf, logd, mlws, Qns, Kns,
                                           mlmn, ldxp,
                                           out + (size_t)MTOT * DMODEL);
}

// Round 7
// 230.020 us; speedup vs baseline: 1.2934x; 1.0019x over previous
//
#include <hip/hip_runtime.h>
#include <math.h>

#define DMODEL 1024
#define NHEAD  16
#define DK     64
#define BB     2
#define LL     2048
#define MTOT   (BB*LL)   // 4096

#define LOG2E      1.4426950408889634f
#define SCQ        (0.125f * LOG2E)    // folded into Q at projection epilogue
#define C2LOG      (0.1f * LOG2E)      // distance coeff in log2 domain
#define SKIP_BOUND (-24.0f)            // skip tile if max log2(P) below this

typedef __bf16 bf16_t;
typedef __bf16 bf16x8 __attribute__((ext_vector_type(8)));
typedef __bf16 bf16x4 __attribute__((ext_vector_type(4)));
typedef float  f32x4  __attribute__((ext_vector_type(4)));

static __device__ __forceinline__ f32x4 mfma16(bf16x8 a, bf16x8 b, f32x4 c) {
    return __builtin_amdgcn_mfma_f32_16x16x32_bf16(a, b, c, 0, 0, 0);
}
static __device__ __forceinline__ float exp2f_fast(float x) {
    return __builtin_amdgcn_exp2f(x);
}
static __device__ __forceinline__ float log2f_fast(float x) {
    return __builtin_amdgcn_logf(x);
}
static __device__ __forceinline__ void gl_lds16(const bf16_t* g, bf16_t* l) {
    __builtin_amdgcn_global_load_lds(
        (const __attribute__((address_space(1))) unsigned int*)g,
        (__attribute__((address_space(3))) unsigned int*)l, 16, 0, 0);
}

// ---------------------------------------------------------------------------
// fused prep: blocks [0,2048): x -> bf16 (+ logd2); blocks [2048,3072):
// W[k][n] f32 -> Wt[n][k] bf16 (transpose + convert), 4 matrices.
// ---------------------------------------------------------------------------
__global__ __launch_bounds__(256) void prep_fused_k(
    const float* __restrict__ x, const float* __restrict__ dr,
    bf16_t* __restrict__ xb, float* __restrict__ logd2,
    const float* __restrict__ Wq, const float* __restrict__ Wk,
    const float* __restrict__ Wv, const float* __restrict__ Wo,
    bf16_t* __restrict__ Wcat, bf16_t* __restrict__ Wot)
{
    __shared__ __align__(16) float Ts[64][68];
    const int bid = blockIdx.x;
    const int tid = threadIdx.x;
    if (bid < 2048) {
        size_t gid = (size_t)bid * 256 + tid;   // 524288 total
        size_t off = gid * 8;
        float4 a = *(const float4*)(x + off);
        float4 c = *(const float4*)(x + off + 4);
        float va[8] = {a.x, a.y, a.z, a.w, c.x, c.y, c.z, c.w};
        bf16x8 o1;
#pragma unroll
        for (int j = 0; j < 8; ++j) o1[j] = (bf16_t)va[j];
        *(bf16x8*)(xb + off) = o1;
        if (gid < MTOT) logd2[gid] = log2f_fast(dr[gid] + 1e-6f);
    } else {
        const int t = bid - 2048;
        const int z = t >> 8;
        const float* W = (z == 0) ? Wq : (z == 1) ? Wk : (z == 2) ? Wv : Wo;
        bf16_t* dst = (z < 3) ? (Wcat + (size_t)z * DMODEL * DMODEL) : Wot;
        const int k0 = (t & 15) * 64, n0 = ((t >> 4) & 15) * 64;
#pragma unroll
        for (int i = 0; i < 4; ++i) {
            int u = tid + 256 * i, r = u >> 4, c4 = (u & 15) * 4;
            *(float4*)&Ts[r][c4] = *(const float4*)(W + (size_t)(k0 + r) * DMODEL + n0 + c4);
        }
        __syncthreads();
#pragma unroll
        for (int i = 0; i < 2; ++i) {
            int u = tid + 256 * i, n = u >> 3, k8 = (u & 7) * 8;
            bf16x8 v;
#pragma unroll
            for (int j = 0; j < 8; ++j) v[j] = (bf16_t)Ts[k8 + j][n];
            *(bf16x8*)(dst + (size_t)(n0 + n) * DMODEL + k0 + k8) = v;
        }
    }
}

// ---------------------------------------------------------------------------
// 128x128 MFMA GEMM, BK=64, global_load_lds + XOR-swizzled LDS.
// QKV epilogue. Q/K regions ALSO write fragment-ordered copies Qf/Kf
// ([bh][t16][kc][quad][n16][8]) for coalesced fragment reads in the tail.
// ---------------------------------------------------------------------------
__global__ __launch_bounds__(256, 3) void gemm128_k(
    const bf16_t* __restrict__ A, const bf16_t* __restrict__ Bt,
    const float* __restrict__ b0, const float* __restrict__ b1,
    const float* __restrict__ b2, const float* __restrict__ delta,
    bf16_t* __restrict__ outQ, bf16_t* __restrict__ outK,
    bf16_t* __restrict__ outVt, bf16_t* __restrict__ outQf,
    bf16_t* __restrict__ outKf)
{
    __shared__ __align__(16) bf16_t Asw[128 * 64];
    __shared__ __align__(16) bf16_t Bsw[128 * 64];
    const int tid = threadIdx.x, lane = tid & 63, w = tid >> 6;
    const int quad = lane >> 4, n16 = lane & 15;
    const int wm = (w & 1) * 64, wn = (w >> 1) * 64;
    const int m0 = blockIdx.y * 128, n0 = blockIdx.x * 128;
    const int srow = lane >> 3;
    const int scb  = (lane & 7) ^ srow;

    f32x4 acc[4][4] = {};

    for (int K0 = 0; K0 < DMODEL; K0 += 64) {
        __syncthreads();
#pragma unroll
        for (int i = 0; i < 4; ++i) {
            int rb = w * 32 + i * 8;
            gl_lds16(A  + (size_t)(m0 + rb + srow) * DMODEL + K0 + scb * 8,
                     &Asw[rb * 64]);
            gl_lds16(Bt + (size_t)(n0 + rb + srow) * DMODEL + K0 + scb * 8,
                     &Bsw[rb * 64]);
        }
        __syncthreads();
#pragma unroll
        for (int kc = 0; kc < 2; ++kc) {
            const int pcb = ((kc * 4 + quad) ^ (n16 & 7)) * 8;
            bf16x8 af[4], bfv[4];
#pragma unroll
            for (int mi = 0; mi < 4; ++mi)
                af[mi] = *(const bf16x8*)&Asw[(wm + mi * 16 + n16) * 64 + pcb];
#pragma unroll
            for (int ni = 0; ni < 4; ++ni)
                bfv[ni] = *(const bf16x8*)&Bsw[(wn + ni * 16 + n16) * 64 + pcb];
#pragma unroll
            for (int mi = 0; mi < 4; ++mi)
#pragma unroll
                for (int ni = 0; ni < 4; ++ni)
                    acc[mi][ni] = mfma16(af[mi], bfv[ni], acc[mi][ni]);
        }
    }

    const int region = n0 >> 10;
    if (region == 2) {
#pragma unroll
        for (int mi = 0; mi < 4; ++mi) {
            const int mbase = m0 + wm + mi * 16 + quad * 4;
            const int bidx = mbase >> 11, l = mbase & (LL - 1);
            const f32x4 dm4 = *(const f32x4*)(delta + mbase);
#pragma unroll
            for (int ni = 0; ni < 4; ++ni) {
                const int nl = (n0 & 1023) + wn + ni * 16 + n16;
                const int h = nl >> 6, dd = nl & 63;
                const float bv = b2[nl];
                bf16x4 pk;
#pragma unroll
                for (int r = 0; r < 4; ++r)
                    pk[r] = (bf16_t)(acc[mi][ni][r] * dm4[r] + bv);
                *(bf16x4*)(outVt + ((size_t)(bidx * NHEAD + h) * DK + dd) * LL + l) = pk;
            }
        }
    } else {
        const float* bias = (region == 0) ? b0 : b1;
        bf16_t* dst = (region == 0) ? outQ : outK;
        bf16_t* fdst = (region == 0) ? outQf : outKf;
        const float qs = (region == 0) ? SCQ : 1.0f;
#pragma unroll
        for (int mi = 0; mi < 4; ++mi) {
#pragma unroll
            for (int r = 0; r < 4; ++r) {
                const int m = m0 + wm + mi * 16 + quad * 4 + r;
                const int bidx = m >> 11, l = m & (LL - 1);
#pragma unroll
                for (int ni = 0; ni < 4; ++ni) {
                    const int nl = (n0 & 1023) + wn + ni * 16 + n16;
                    const int h = nl >> 6, dd = nl & 63;
                    float v = (acc[mi][ni][r] + bias[nl]) * qs;
                    bf16_t bv16 = (bf16_t)v;
                    dst[(((size_t)(bidx * NHEAD + h) * LL) + l) * DK + dd] = bv16;
                    // fragment layout: [bh][t16=l>>4][kc=dd>>5][quad=(dd>>3)&3][n16=l&15][e=dd&7]
                    fdst[(((size_t)(bidx * NHEAD + h) * (LL >> 4) + (l >> 4)) * 8 +
                          (dd >> 5) * 4 + ((dd >> 3) & 3)) * 128 +
                         (l & 15) * 8 + (dd & 7)] = bv16;
                }
            }
        }
    }
}

// ---------------------------------------------------------------------------
// stats, 256 blocks (8 segments x 256 rows per (b,h)).
// ---------------------------------------------------------------------------
__global__ __launch_bounds__(256) void stats_k(
    const bf16_t* __restrict__ Q, const bf16_t* __restrict__ K,
    const float* __restrict__ logd2, float* __restrict__ Qn,
    float* __restrict__ Kn, float* __restrict__ dlb, float* __restrict__ ldx)
{
    __shared__ float qn_s[256], kn_s[256], dg_s[256];
    const int blk = blockIdx.x;
    const int bh = blk >> 3, seg = blk & 7, b = bh >> 4;
    const int tid = threadIdx.x;
    const int row = seg * 256 + tid;
    const size_t base = (size_t)bh * LL * DK;

    float qn2 = 0.f, kn2 = 0.f, dg = 0.f;
#pragma unroll
    for (int j = 0; j < 8; ++j) {
        bf16x8 qv = *(const bf16x8*)(Q + base + (size_t)row * DK + j * 8);
        bf16x8 kv = *(const bf16x8*)(K + base + (size_t)row * DK + j * 8);
#pragma unroll
        for (int e = 0; e < 8; ++e) {
            float fq = (float)qv[e], fk = (float)kv[e];
            qn2 += fq * fq; kn2 += fk * fk; dg += fq * fk;
        }
    }
    qn_s[tid] = qn2;
    kn_s[tid] = kn2;
    dg_s[tid] = dg + logd2[b * LL + row];
    __syncthreads();

    if (tid < 2) {               // 2 q-tiles of 128 rows in this segment
        float mq = 0.f, md = 1e30f;
        for (int r = 0; r < 128; ++r) {
            mq = fmaxf(mq, qn_s[tid * 128 + r]);
            md = fminf(md, dg_s[tid * 128 + r]);
        }
        Qn[bh * 16 + seg * 2 + tid] = sqrtf(mq);
        dlb[bh * 16 + seg * 2 + tid] = md;
    } else if (tid >= 64 && tid < 68) {   // 4 k-tiles of 64 rows
        const int t = tid - 64;
        float mk = 0.f;
        for (int r = 0; r < 64; ++r) mk = fmaxf(mk, kn_s[t * 64 + r]);
        Kn[bh * 32 + seg * 4 + t] = sqrtf(mk);
    } else if (tid >= 128 && tid < 132 && (bh & 15) == 0) {
        const int t = tid - 128;
        float ml = -1e30f;
        for (int r = 0; r < 64; ++r)
            ml = fmaxf(ml, logd2[b * LL + seg * 256 + t * 64 + r]);
        ldx[b * 32 + seg * 4 + t] = ml;
    }
}

// ---------------------------------------------------------------------------
// mlmin[bh][qtile16] = min over 128 q of ml (after flash)
// ---------------------------------------------------------------------------
__global__ __launch_bounds__(256) void mlstat_k(
    const float* __restrict__ mlws, float* __restrict__ mlmin)
{
    __shared__ float s[2048];
    const int tid = threadIdx.x, bh = blockIdx.x;
#pragma unroll
    for (int i = 0; i < 8; ++i)
        s[tid + 256 * i] = mlws[(size_t)bh * LL + tid + 256 * i];
    __syncthreads();
    if (tid < 16) {
        float m = 1e30f;
        for (int r = 0; r < 128; ++r) m = fminf(m, s[tid * 128 + r]);
        mlmin[bh * 16 + tid] = m;
    }
}

// ---------------------------------------------------------------------------
// MFMA flash attention, S^T form, 64 q/block (1024 blocks -> 16 waves/CU),
// sound far-tile skip (stats indexed by 128-q supertile: still sound bounds).
// ---------------------------------------------------------------------------
__global__ __launch_bounds__(256, 4) void attn_flash_mfma_k(
    const bf16_t* __restrict__ Q, const bf16_t* __restrict__ K,
    const bf16_t* __restrict__ Vt, const float* __restrict__ logd2,
    const float* __restrict__ Qn, const float* __restrict__ Kn,
    const float* __restrict__ dlb, const float* __restrict__ ldx,
    bf16_t* __restrict__ ctx, float* __restrict__ mlout)
{
    __shared__ __align__(16) bf16_t Ks[64][72];
    __shared__ __align__(16) bf16_t Vts[64][72];
    __shared__ __align__(16) bf16_t Ps[4][16][72];
    __shared__ float logds[64];

    const int tid = threadIdx.x;
    const int lane = tid & 63, w = tid >> 6;
    const int quad = lane >> 4, n16 = lane & 15;
    const int bh = blockIdx.x, b = bh >> 4, h = bh & 15;
    const int qt = blockIdx.y, q0 = qt * 64;
    const size_t base = (size_t)bh * LL * DK;
    const int q = q0 + w * 16 + n16;

    bf16x8 qa[2];
#pragma unroll
    for (int kc = 0; kc < 2; ++kc)
        qa[kc] = *(const bf16x8*)(Q + base + (size_t)q * DK + kc * 32 + quad * 8);

    // active-tile mask (block-uniform); stats are per 128-q supertile
    unsigned mask = 0;
    {
        const float qn = Qn[bh * 16 + (qt >> 1)], dl = dlb[bh * 16 + (qt >> 1)];
        for (int t = 0; t < 32; ++t) {
            const int kc0 = t * 64;
            const int dmin = (kc0 > q0 + 63) ? (kc0 - (q0 + 63))
                           : ((q0 > kc0 + 63) ? (q0 - (kc0 + 63)) : 0);
            const float bound = qn * Kn[bh * 32 + t] + ldx[b * 32 + t]
                              - C2LOG * (float)dmin - dl;
            if (bound > SKIP_BOUND) mask |= (1u << t);
        }
    }

    const int strow = tid >> 3, stc8 = (tid & 7) * 8;
    bf16x8 kr0, kr1, vr0, vr1;
    float ldr = 0.f;
    auto prefetch = [&](int k0) {
        kr0 = *(const bf16x8*)(K + base + (size_t)(k0 + strow) * DK + stc8);
        kr1 = *(const bf16x8*)(K + base + (size_t)(k0 + 32 + strow) * DK + stc8);
        vr0 = *(const bf16x8*)(Vt + base + (size_t)strow * LL + k0 + stc8);
        vr1 = *(const bf16x8*)(Vt + base + (size_t)(32 + strow) * LL + k0 + stc8);
        if (tid < 64) ldr = logd2[b * LL + k0 + tid];
    };

    float m_c = -1e30f, l_c = 0.f;
    f32x4 o[4] = {};
    const float dfq = (float)(q - quad * 4);

    int t = (int)__builtin_ctz(mask);   // mask != 0 guaranteed (diagonal)
    prefetch(t * 64);
    for (;;) {
        const unsigned rem = (t < 31) ? (mask >> (t + 1)) : 0u;
        const int tn = rem ? (t + 1 + (int)__builtin_ctz(rem)) : -1;
        __syncthreads();
        *(bf16x8*)&Ks[strow][stc8]       = kr0;
        *(bf16x8*)&Ks[32 + strow][stc8]  = kr1;
        *(bf16x8*)&Vts[strow][stc8]      = vr0;
        *(bf16x8*)&Vts[32 + strow][stc8] = vr1;
        if (tid < 64) logds[tid] = ldr;
        __syncthreads();
        if (tn >= 0) prefetch(tn * 64);
        const int k0 = t * 64;

        f32x4 s[4] = {};
#pragma unroll
        for (int kc = 0; kc < 2; ++kc) {
#pragma unroll
            for (int kt = 0; kt < 4; ++kt) {
                bf16x8 kb = *(const bf16x8*)&Ks[kt * 16 + n16][kc * 32 + quad * 8];
                s[kt] = mfma16(kb, qa[kc], s[kt]);
            }
        }
        const float df = dfq - (float)k0;
#pragma unroll
        for (int kt = 0; kt < 4; ++kt) {
            f32x4 ldv = *(const f32x4*)&logds[kt * 16 + quad * 4];
#pragma unroll
            for (int r = 0; r < 4; ++r)
                s[kt][r] += ldv[r] - C2LOG * fabsf(df - (float)(kt * 16 + r));
        }
        f32x4 mx;
#pragma unroll
        for (int r = 0; r < 4; ++r)
            mx[r] = fmaxf(fmaxf(s[0][r], s[1][r]), fmaxf(s[2][r], s[3][r]));
        float rm = fmaxf(fmaxf(mx[0], mx[1]), fmaxf(mx[2], mx[3]));
        rm = fmaxf(rm, __shfl_xor(rm, 16));
        rm = fmaxf(rm, __shfl_xor(rm, 32));
        const float mn = fmaxf(m_c, rm);
        const float alpha = exp2f_fast(m_c - mn);
        if (__any(mn > m_c)) {
#pragma unroll
            for (int dt = 0; dt < 4; ++dt)
#pragma unroll
                for (int r = 0; r < 4; ++r) o[dt][r] *= alpha;
        }
        f32x4 ps = {0.f, 0.f, 0.f, 0.f};
#pragma unroll
        for (int kt = 0; kt < 4; ++kt)
#pragma unroll
            for (int r = 0; r < 4; ++r) {
                float p = exp2f_fast(s[kt][r] - mn);
                s[kt][r] = p;
                ps[r] += p;
            }
        float psum = (ps[0] + ps[1]) + (ps[2] + ps[3]);
        psum += __shfl_xor(psum, 16);
        psum += __shfl_xor(psum, 32);
        l_c = l_c * alpha + psum;
        m_c = mn;
#pragma unroll
        for (int kt = 0; kt < 4; ++kt) {
            bf16x4 pk;
#pragma unroll
            for (int r = 0; r < 4; ++r) pk[r] = (bf16_t)s[kt][r];
            *(bf16x4*)&Ps[w][n16][kt * 16 + quad * 4] = pk;
        }
        __threadfence_block();
#pragma unroll
        for (int kc = 0; kc < 2; ++kc) {
            bf16x8 pa = *(const bf16x8*)&Ps[w][n16][kc * 32 + quad * 8];
#pragma unroll
            for (int dt = 0; dt < 4; ++dt) {
                bf16x8 vb = *(const bf16x8*)&Vts[dt * 16 + n16][kc * 32 + quad * 8];
                o[dt] = mfma16(vb, pa, o[dt]);
            }
        }
        if (tn < 0) break;
        t = tn;
    }
    const float inv = 1.f / l_c;
#pragma unroll
    for (int dt = 0; dt < 4; ++dt) {
        bf16x4 ov;
#pragma unroll
        for (int r = 0; r < 4; ++r) ov[r] = (bf16_t)(o[dt][r] * inv);
        *(bf16x4*)(ctx + ((size_t)b * LL + q) * DMODEL + h * DK +
                   dt * 16 + quad * 4) = ov;
    }
    if (quad == 0)
        mlout[(size_t)bh * LL + q] = m_c + log2f_fast(l_c);
}

// ---------------------------------------------------------------------------
// fused tail. blocks [0,4096): attn.mean — HEAD-SPLIT-ACROSS-WAVES:
// block = (b, 32 q-rows, 64 k-cols); wave w handles heads {h: h%4==w}
// (<=4 serial head-iters vs 16 — R6 diagnosis: the 16-head serial chain per
// wave was the latency-bound critical path of the heavy near-diagonal
// blocks). Coalesced Qf/Kf fragment reads (R6), barrier-free inner loop,
// one LDS combine at the end. Tiles rank-major (diagonal-first) so the
// ~1024 heavy tiles own the machine from t=0; gemm blocks [4096,4608)
// backfill (output-projection, verified gemm_out_k body).
// ---------------------------------------------------------------------------
__global__ __launch_bounds__(256, 3) void tail_fused_k(
    const bf16_t* __restrict__ A, const bf16_t* __restrict__ Bt,
    const float* __restrict__ b0, float* __restrict__ outf,
    const bf16_t* __restrict__ Qf, const bf16_t* __restrict__ Kf,
    const float* __restrict__ logd2, const float* __restrict__ mlws,
    const float* __restrict__ Qn, const float* __restrict__ Kn,
    const float* __restrict__ mlmin, const float* __restrict__ ldx,
    float* __restrict__ outmean)
{
    // union: gemm branch Asw(8192)+Bsw(16384)=24576 B;
    // mean branch cmb[4][32][68] f32 = 34816 B.
    __shared__ __align__(16) char smem[34816];

    const int bid = blockIdx.x;
    const int tid = threadIdx.x;
    const int lane = tid & 63, w = tid >> 6;
    const int quad = lane >> 4, n16 = lane & 15;

    if (bid >= 4096) {
        // ---------------- output projection GEMM (verified gemm_out_k body)
        bf16_t* Asw = (bf16_t*)smem;
        bf16_t* Bsw = (bf16_t*)(smem + 8192);
        const int gb = bid - 4096;
        const int wm = (w & 1) * 32, wn = (w >> 1) * 64;
        const int m0 = (gb >> 3) * 64, n0 = (gb & 7) * 128;
        const int srow = lane >> 3;
        const int scb  = (lane & 7) ^ srow;

        f32x4 acc[2][4] = {};

        for (int K0 = 0; K0 < DMODEL; K0 += 64) {
            __syncthreads();
#pragma unroll
            for (int i = 0; i < 2; ++i) {
                int rb = w * 16 + i * 8;
                gl_lds16(A + (size_t)(m0 + rb + srow) * DMODEL + K0 + scb * 8,
                         &Asw[rb * 64]);
            }
#pragma unroll
            for (int i = 0; i < 4; ++i) {
                int rb = w * 32 + i * 8;
                gl_lds16(Bt + (size_t)(n0 + rb + srow) * DMODEL + K0 + scb * 8,
                         &Bsw[rb * 64]);
            }
            __syncthreads();
#pragma unroll
            for (int kc = 0; kc < 2; ++kc) {
                const int pcb = ((kc * 4 + quad) ^ (n16 & 7)) * 8;
                bf16x8 af[2], bfv[4];
#pragma unroll
                for (int mi = 0; mi < 2; ++mi)
                    af[mi] = *(const bf16x8*)&Asw[(wm + mi * 16 + n16) * 64 + pcb];
#pragma unroll
                for (int ni = 0; ni < 4; ++ni)
                    bfv[ni] = *(const bf16x8*)&Bsw[(wn + ni * 16 + n16) * 64 + pcb];
#pragma unroll
                for (int mi = 0; mi < 2; ++mi)
#pragma unroll
                    for (int ni = 0; ni < 4; ++ni)
                        acc[mi][ni] = mfma16(af[mi], bfv[ni], acc[mi][ni]);
            }
        }
#pragma unroll
        for (int mi = 0; mi < 2; ++mi) {
#pragma unroll
            for (int r = 0; r < 4; ++r) {
                const int m = m0 + wm + mi * 16 + quad * 4 + r;
#pragma unroll
                for (int ni = 0; ni < 4; ++ni) {
                    const int n = n0 + wn + ni * 16 + n16;
                    outf[(size_t)m * DMODEL + n] = acc[mi][ni][r] + b0[n];
                }
            }
        }
        return;
    }

    // ---------------- attn.mean: rank-major tile decode ------------------
    // m = rank*128 + (b*64 + q32): all heaviest (rank 0) tiles first.
    const int m = bid;
    const int rank = m >> 7, bq = m & 127, b = bq >> 6, q32 = bq & 63;
    const int q0 = q32 * 32;

    int ktile = 0;
    {
        const int c = q0 >> 6;       // diagonal k-tile of this 32-row band
        int want = rank;
        for (int d = 0; d < 32; ++d) {
            int ka = c - d, kb2 = c + 1 + d;
            if (ka >= 0 && ka < 32) {
                if (want == 0) { ktile = ka; break; }
                --want;
            }
            if (kb2 >= 0 && kb2 < 32) {
                if (want == 0) { ktile = kb2; break; }
                --want;
            }
        }
    }
    const int k0 = ktile * 64;

    const int qt = q0 >> 7;          // stats supertile
    const int dmin = (k0 > q0 + 31) ? (k0 - (q0 + 31))
                   : ((q0 > k0 + 63) ? (q0 - (k0 + 63)) : 0);
    unsigned hmask = 0;
    {
        const float dterm = ldx[b * 32 + ktile] - C2LOG * (float)dmin;
        for (int h = 0; h < NHEAD; ++h) {
            const int bh = b * 16 + h;
            const float bound = Qn[bh * 16 + qt] * Kn[bh * 32 + ktile] + dterm
                              - mlmin[bh * 16 + qt];
            if (bound > SKIP_BOUND) hmask |= (1u << h);
        }
    }

    if (!hmask) {
        // write 32x64 zeros, 8 floats/thread
        const int row = tid >> 3, c8 = (tid & 7) * 8;
        const f32x4 z = {0.f, 0.f, 0.f, 0.f};
        float* dst = outmean + ((size_t)b * LL + q0 + row) * LL + k0 + c8;
        *(f32x4*)dst = z;
        *(f32x4*)(dst + 4) = z;
        return;
    }

    const int qq0 = q0 + n16, qq1 = q0 + 16 + n16;

    float bias0[2][4][4];
#pragma unroll
    for (int qg = 0; qg < 2; ++qg) {
        const float df = (float)((qg ? qq1 : qq0) - k0 - quad * 4);
#pragma unroll
        for (int kt = 0; kt < 4; ++kt) {
            const f32x4 ldv = *(const f32x4*)(logd2 + b * LL + k0 + kt * 16 + quad * 4);
#pragma unroll
            for (int r = 0; r < 4; ++r)
                bias0[qg][kt][r] = ldv[r] - C2LOG * fabsf(df - (float)(kt * 16 + r));
        }
    }

    f32x4 acc[2][4] = {};
    {
        const int kt16 = k0 >> 4, qt16 = q0 >> 4;
#pragma unroll
        for (int i = 0; i < 4; ++i) {
            const int h = w + i * 4;          // wave-uniform head subset
            if (!(hmask & (1u << h))) continue;
            const size_t hb = (size_t)(b * NHEAD + h) * LL * DK;

            const float ml0 = mlws[(size_t)(b * NHEAD + h) * LL + qq0];
            const float ml1 = mlws[(size_t)(b * NHEAD + h) * LL + qq1];

            f32x4 s[2][4] = {};
#pragma unroll
            for (int kc = 0; kc < 2; ++kc) {
                bf16x8 kbf[4];
#pragma unroll
                for (int kt = 0; kt < 4; ++kt)
                    kbf[kt] = *(const bf16x8*)(Kf + hb +
                              ((size_t)(kt16 + kt) * 8 + kc * 4 + quad) * 128 +
                              n16 * 8);
                const bf16x8 qc0 = *(const bf16x8*)(Qf + hb +
                              ((size_t)qt16 * 8 + kc * 4 + quad) * 128 + n16 * 8);
                const bf16x8 qc1 = *(const bf16x8*)(Qf + hb +
                              ((size_t)(qt16 + 1) * 8 + kc * 4 + quad) * 128 + n16 * 8);
#pragma unroll
                for (int kt = 0; kt < 4; ++kt) {
                    s[0][kt] = mfma16(kbf[kt], qc0, s[0][kt]);
                    s[1][kt] = mfma16(kbf[kt], qc1, s[1][kt]);
                }
            }
#pragma unroll
            for (int kt = 0; kt < 4; ++kt) {
#pragma unroll
                for (int r = 0; r < 4; ++r) {
                    acc[0][kt][r] += exp2f_fast(s[0][kt][r] + bias0[0][kt][r] - ml0);
                    acc[1][kt][r] += exp2f_fast(s[1][kt][r] + bias0[1][kt][r] - ml1);
                }
            }
        }
    }

    // combine 4 wave planes via LDS
    float (*cmb)[32][68] = (float(*)[32][68])smem;
#pragma unroll
    for (int qg = 0; qg < 2; ++qg)
#pragma unroll
        for (int kt = 0; kt < 4; ++kt)
            *(f32x4*)&cmb[w][qg * 16 + n16][kt * 16 + quad * 4] = acc[qg][kt];
    __syncthreads();

    const float invH = 1.f / (float)NHEAD;
    const int row = tid >> 3, c8 = (tid & 7) * 8;
    f32x4 s0 = {0.f, 0.f, 0.f, 0.f}, s1 = {0.f, 0.f, 0.f, 0.f};
#pragma unroll
    for (int w4 = 0; w4 < 4; ++w4) {
        s0 += *(const f32x4*)&cmb[w4][row][c8];
        s1 += *(const f32x4*)&cmb[w4][row][c8 + 4];
    }
#pragma unroll
    for (int r = 0; r < 4; ++r) { s0[r] *= invH; s1[r] *= invH; }
    float* dst = outmean + ((size_t)b * LL + q0 + row) * LL + k0 + c8;
    *(f32x4*)dst = s0;
    *(f32x4*)(dst + 4) = s1;
}

// ---------------------------------------------------------------------------
extern "C" void kernel_launch(void* const* d_in, const int* in_sizes, int n_in,
                              void* d_out, int out_size, void* d_ws, size_t ws_size,
                              hipStream_t stream) {
    const float* x  = (const float*)d_in[0];
    const float* dr = (const float*)d_in[1];
    const float* Wq = (const float*)d_in[2];
    const float* bq = (const float*)d_in[3];
    const float* Wk = (const float*)d_in[4];
    const float* bk = (const float*)d_in[5];
    const float* Wv = (const float*)d_in[6];
    const float* bv = (const float*)d_in[7];
    const float* Wo = (const float*)d_in[8];
    const float* bo = (const float*)d_in[9];
    float* out = (float*)d_out;
    char* ws = (char*)d_ws;
    const size_t MB = 1ull << 20;

    bf16_t* xb   = (bf16_t*)(ws);             // 8 MB; reused as ctx after QKV gemm
    bf16_t* Wcat = (bf16_t*)(ws + 8 * MB);    // 6 MB  [3072][1024]
    bf16_t* Wot  = (bf16_t*)(ws + 14 * MB);   // 2 MB
    bf16_t* Qb   = (bf16_t*)(ws + 16 * MB);   // 8 MB
    bf16_t* Kb   = (bf16_t*)(ws + 24 * MB);   // 8 MB
    bf16_t* Vtb  = (bf16_t*)(ws + 32 * MB);   // 8 MB  [b,h,dk,l]
    float*  logd = (float*)(ws + 40 * MB);    // 16 KB
    float*  mlws = (float*)(ws + 41 * MB);    // 256 KB
    float*  Qns  = (float*)(ws + 42 * MB);            // [32][16]
    float*  Kns  = (float*)(ws + 42 * MB + 4096);     // [32][32]
    float*  dlb  = (float*)(ws + 42 * MB + 12288);    // [32][16]
    float*  ldxp = (float*)(ws + 42 * MB + 16384);    // [2][32]
    float*  mlmn = (float*)(ws + 42 * MB + 20480);    // [32][16]
    bf16_t* Kf   = (bf16_t*)(ws + 43 * MB);   // 8 MB fragment-ordered K
    bf16_t* Qf   = (bf16_t*)(ws + 51 * MB);   // 8 MB fragment-ordered Q
    bf16_t* ctx  = xb;

    prep_fused_k<<<3072, 256, 0, stream>>>(x, dr, xb, logd,
                                           Wq, Wk, Wv, Wo, Wcat, Wot);

    gemm128_k<<<dim3(24, 32), 256, 0, stream>>>(xb, Wcat, bq, bk, bv, dr,
                                                Qb, Kb, Vtb, Qf, Kf);
    stats_k<<<256, 256, 0, stream>>>(Qb, Kb, logd, Qns, Kns, dlb, ldxp);

    attn_flash_mfma_k<<<dim3(32, 32), 256, 0, stream>>>(Qb, Kb, Vtb, logd,
                                                        Qns, Kns, dlb, ldxp,
                                                        ctx, mlws);
    mlstat_k<<<32, 256, 0, stream>>>(mlws, mlmn);
    tail_fused_k<<<4608, 256, 0, stream>>>(ctx, Wot, bo, out,
                                           Qf, Kf, logd, mlws, Qns, Kns,
                                           mlmn, ldxp,
                                           out + (size_t)MTOT * DMODEL);
}

// Round 8
// 213.932 us; speedup vs baseline: 1.3906x; 1.0752x over previous
//
#include <hip/hip_runtime.h>
#include <math.h>

#define DMODEL 1024
#define NHEAD  16
#define DK     64
#define BB     2
#define LL     2048
#define MTOT   (BB*LL)   // 4096

#define LOG2E      1.4426950408889634f
#define SCQ        (0.125f * LOG2E)    // folded into Q at projection epilogue
#define C2LOG      (0.1f * LOG2E)      // distance coeff in log2 domain
#define SKIP_BOUND (-24.0f)            // skip tile if max log2(P) below this

typedef __bf16 bf16_t;
typedef __bf16 bf16x8 __attribute__((ext_vector_type(8)));
typedef __bf16 bf16x4 __attribute__((ext_vector_type(4)));
typedef float  f32x4  __attribute__((ext_vector_type(4)));

static __device__ __forceinline__ f32x4 mfma16(bf16x8 a, bf16x8 b, f32x4 c) {
    return __builtin_amdgcn_mfma_f32_16x16x32_bf16(a, b, c, 0, 0, 0);
}
static __device__ __forceinline__ float exp2f_fast(float x) {
    return __builtin_amdgcn_exp2f(x);
}
static __device__ __forceinline__ float log2f_fast(float x) {
    return __builtin_amdgcn_logf(x);
}
static __device__ __forceinline__ void gl_lds16(const bf16_t* g, bf16_t* l) {
    __builtin_amdgcn_global_load_lds(
        (const __attribute__((address_space(1))) unsigned int*)g,
        (__attribute__((address_space(3))) unsigned int*)l, 16, 0, 0);
}

// ---------------------------------------------------------------------------
// fused prep: blocks [0,2048): x -> bf16 (+ logd2); blocks [2048,3072):
// W[k][n] f32 -> Wt[n][k] bf16 (transpose + convert), 4 matrices.
// ---------------------------------------------------------------------------
__global__ __launch_bounds__(256) void prep_fused_k(
    const float* __restrict__ x, const float* __restrict__ dr,
    bf16_t* __restrict__ xb, float* __restrict__ logd2,
    const float* __restrict__ Wq, const float* __restrict__ Wk,
    const float* __restrict__ Wv, const float* __restrict__ Wo,
    bf16_t* __restrict__ Wcat, bf16_t* __restrict__ Wot)
{
    __shared__ __align__(16) float Ts[64][68];
    const int bid = blockIdx.x;
    const int tid = threadIdx.x;
    if (bid < 2048) {
        size_t gid = (size_t)bid * 256 + tid;   // 524288 total
        size_t off = gid * 8;
        float4 a = *(const float4*)(x + off);
        float4 c = *(const float4*)(x + off + 4);
        float va[8] = {a.x, a.y, a.z, a.w, c.x, c.y, c.z, c.w};
        bf16x8 o1;
#pragma unroll
        for (int j = 0; j < 8; ++j) o1[j] = (bf16_t)va[j];
        *(bf16x8*)(xb + off) = o1;
        if (gid < MTOT) logd2[gid] = log2f_fast(dr[gid] + 1e-6f);
    } else {
        const int t = bid - 2048;
        const int z = t >> 8;
        const float* W = (z == 0) ? Wq : (z == 1) ? Wk : (z == 2) ? Wv : Wo;
        bf16_t* dst = (z < 3) ? (Wcat + (size_t)z * DMODEL * DMODEL) : Wot;
        const int k0 = (t & 15) * 64, n0 = ((t >> 4) & 15) * 64;
#pragma unroll
        for (int i = 0; i < 4; ++i) {
            int u = tid + 256 * i, r = u >> 4, c4 = (u & 15) * 4;
            *(float4*)&Ts[r][c4] = *(const float4*)(W + (size_t)(k0 + r) * DMODEL + n0 + c4);
        }
        __syncthreads();
#pragma unroll
        for (int i = 0; i < 2; ++i) {
            int u = tid + 256 * i, n = u >> 3, k8 = (u & 7) * 8;
            bf16x8 v;
#pragma unroll
            for (int j = 0; j < 8; ++j) v[j] = (bf16_t)Ts[k8 + j][n];
            *(bf16x8*)(dst + (size_t)(n0 + n) * DMODEL + k0 + k8) = v;
        }
    }
}

// ---------------------------------------------------------------------------
// 128x128 MFMA GEMM, BK=64, global_load_lds + XOR-swizzled LDS.
// QKV epilogue (Q prescaled SCQ; V written transposed+scaled). R4-verified
// form (Qf/Kf fragment stores removed with the R6/R7 tail experiments).
// ---------------------------------------------------------------------------
__global__ __launch_bounds__(256, 3) void gemm128_k(
    const bf16_t* __restrict__ A, const bf16_t* __restrict__ Bt,
    const float* __restrict__ b0, const float* __restrict__ b1,
    const float* __restrict__ b2, const float* __restrict__ delta,
    bf16_t* __restrict__ outQ, bf16_t* __restrict__ outK,
    bf16_t* __restrict__ outVt)
{
    __shared__ __align__(16) bf16_t Asw[128 * 64];
    __shared__ __align__(16) bf16_t Bsw[128 * 64];
    const int tid = threadIdx.x, lane = tid & 63, w = tid >> 6;
    const int quad = lane >> 4, n16 = lane & 15;
    const int wm = (w & 1) * 64, wn = (w >> 1) * 64;
    const int m0 = blockIdx.y * 128, n0 = blockIdx.x * 128;
    const int srow = lane >> 3;
    const int scb  = (lane & 7) ^ srow;

    f32x4 acc[4][4] = {};

    for (int K0 = 0; K0 < DMODEL; K0 += 64) {
        __syncthreads();
#pragma unroll
        for (int i = 0; i < 4; ++i) {
            int rb = w * 32 + i * 8;
            gl_lds16(A  + (size_t)(m0 + rb + srow) * DMODEL + K0 + scb * 8,
                     &Asw[rb * 64]);
            gl_lds16(Bt + (size_t)(n0 + rb + srow) * DMODEL + K0 + scb * 8,
                     &Bsw[rb * 64]);
        }
        __syncthreads();
#pragma unroll
        for (int kc = 0; kc < 2; ++kc) {
            const int pcb = ((kc * 4 + quad) ^ (n16 & 7)) * 8;
            bf16x8 af[4], bfv[4];
#pragma unroll
            for (int mi = 0; mi < 4; ++mi)
                af[mi] = *(const bf16x8*)&Asw[(wm + mi * 16 + n16) * 64 + pcb];
#pragma unroll
            for (int ni = 0; ni < 4; ++ni)
                bfv[ni] = *(const bf16x8*)&Bsw[(wn + ni * 16 + n16) * 64 + pcb];
#pragma unroll
            for (int mi = 0; mi < 4; ++mi)
#pragma unroll
                for (int ni = 0; ni < 4; ++ni)
                    acc[mi][ni] = mfma16(af[mi], bfv[ni], acc[mi][ni]);
        }
    }

    const int region = n0 >> 10;
    if (region == 2) {
#pragma unroll
        for (int mi = 0; mi < 4; ++mi) {
            const int mbase = m0 + wm + mi * 16 + quad * 4;
            const int bidx = mbase >> 11, l = mbase & (LL - 1);
            const f32x4 dm4 = *(const f32x4*)(delta + mbase);
#pragma unroll
            for (int ni = 0; ni < 4; ++ni) {
                const int nl = (n0 & 1023) + wn + ni * 16 + n16;
                const int h = nl >> 6, dd = nl & 63;
                const float bv = b2[nl];
                bf16x4 pk;
#pragma unroll
                for (int r = 0; r < 4; ++r)
                    pk[r] = (bf16_t)(acc[mi][ni][r] * dm4[r] + bv);
                *(bf16x4*)(outVt + ((size_t)(bidx * NHEAD + h) * DK + dd) * LL + l) = pk;
            }
        }
    } else {
        const float* bias = (region == 0) ? b0 : b1;
        bf16_t* dst = (region == 0) ? outQ : outK;
        const float qs = (region == 0) ? SCQ : 1.0f;
#pragma unroll
        for (int mi = 0; mi < 4; ++mi) {
#pragma unroll
            for (int r = 0; r < 4; ++r) {
                const int m = m0 + wm + mi * 16 + quad * 4 + r;
                const int bidx = m >> 11, l = m & (LL - 1);
#pragma unroll
                for (int ni = 0; ni < 4; ++ni) {
                    const int nl = (n0 & 1023) + wn + ni * 16 + n16;
                    const int h = nl >> 6, dd = nl & 63;
                    float v = (acc[mi][ni][r] + bias[nl]) * qs;
                    dst[(((size_t)(bidx * NHEAD + h) * LL) + l) * DK + dd] = (bf16_t)v;
                }
            }
        }
    }
}

// ---------------------------------------------------------------------------
// stats, 256 blocks (8 segments x 256 rows per (b,h)).
// ---------------------------------------------------------------------------
__global__ __launch_bounds__(256) void stats_k(
    const bf16_t* __restrict__ Q, const bf16_t* __restrict__ K,
    const float* __restrict__ logd2, float* __restrict__ Qn,
    float* __restrict__ Kn, float* __restrict__ dlb, float* __restrict__ ldx)
{
    __shared__ float qn_s[256], kn_s[256], dg_s[256];
    const int blk = blockIdx.x;
    const int bh = blk >> 3, seg = blk & 7, b = bh >> 4;
    const int tid = threadIdx.x;
    const int row = seg * 256 + tid;
    const size_t base = (size_t)bh * LL * DK;

    float qn2 = 0.f, kn2 = 0.f, dg = 0.f;
#pragma unroll
    for (int j = 0; j < 8; ++j) {
        bf16x8 qv = *(const bf16x8*)(Q + base + (size_t)row * DK + j * 8);
        bf16x8 kv = *(const bf16x8*)(K + base + (size_t)row * DK + j * 8);
#pragma unroll
        for (int e = 0; e < 8; ++e) {
            float fq = (float)qv[e], fk = (float)kv[e];
            qn2 += fq * fq; kn2 += fk * fk; dg += fq * fk;
        }
    }
    qn_s[tid] = qn2;
    kn_s[tid] = kn2;
    dg_s[tid] = dg + logd2[b * LL + row];
    __syncthreads();

    if (tid < 2) {               // 2 q-tiles of 128 rows in this segment
        float mq = 0.f, md = 1e30f;
        for (int r = 0; r < 128; ++r) {
            mq = fmaxf(mq, qn_s[tid * 128 + r]);
            md = fminf(md, dg_s[tid * 128 + r]);
        }
        Qn[bh * 16 + seg * 2 + tid] = sqrtf(mq);
        dlb[bh * 16 + seg * 2 + tid] = md;
    } else if (tid >= 64 && tid < 68) {   // 4 k-tiles of 64 rows
        const int t = tid - 64;
        float mk = 0.f;
        for (int r = 0; r < 64; ++r) mk = fmaxf(mk, kn_s[t * 64 + r]);
        Kn[bh * 32 + seg * 4 + t] = sqrtf(mk);
    } else if (tid >= 128 && tid < 132 && (bh & 15) == 0) {
        const int t = tid - 128;
        float ml = -1e30f;
        for (int r = 0; r < 64; ++r)
            ml = fmaxf(ml, logd2[b * LL + seg * 256 + t * 64 + r]);
        ldx[b * 32 + seg * 4 + t] = ml;
    }
}

// ---------------------------------------------------------------------------
// MFMA flash attention, S^T form, 64 q/block. ALSO emits mlmin64[bh][qt64] =
// min over the block's 64 q of (m + log2 l) — replaces the mlstat_k launch
// (shfl-min + 1 LDS slot + 1 barrier; all quads hold identical m_c/l_c).
// ---------------------------------------------------------------------------
__global__ __launch_bounds__(256, 4) void attn_flash_mfma_k(
    const bf16_t* __restrict__ Q, const bf16_t* __restrict__ K,
    const bf16_t* __restrict__ Vt, const float* __restrict__ logd2,
    const float* __restrict__ Qn, const float* __restrict__ Kn,
    const float* __restrict__ dlb, const float* __restrict__ ldx,
    bf16_t* __restrict__ ctx, float* __restrict__ mlout,
    float* __restrict__ mlmin64)
{
    __shared__ __align__(16) bf16_t Ks[64][72];
    __shared__ __align__(16) bf16_t Vts[64][72];
    __shared__ __align__(16) bf16_t Ps[4][16][72];
    __shared__ float logds[64];
    __shared__ float wvmin[4];

    const int tid = threadIdx.x;
    const int lane = tid & 63, w = tid >> 6;
    const int quad = lane >> 4, n16 = lane & 15;
    const int bh = blockIdx.x, b = bh >> 4, h = bh & 15;
    const int qt = blockIdx.y, q0 = qt * 64;
    const size_t base = (size_t)bh * LL * DK;
    const int q = q0 + w * 16 + n16;

    bf16x8 qa[2];
#pragma unroll
    for (int kc = 0; kc < 2; ++kc)
        qa[kc] = *(const bf16x8*)(Q + base + (size_t)q * DK + kc * 32 + quad * 8);

    // active-tile mask (block-uniform); stats are per 128-q supertile
    unsigned mask = 0;
    {
        const float qn = Qn[bh * 16 + (qt >> 1)], dl = dlb[bh * 16 + (qt >> 1)];
        for (int t = 0; t < 32; ++t) {
            const int kc0 = t * 64;
            const int dmin = (kc0 > q0 + 63) ? (kc0 - (q0 + 63))
                           : ((q0 > kc0 + 63) ? (q0 - (kc0 + 63)) : 0);
            const float bound = qn * Kn[bh * 32 + t] + ldx[b * 32 + t]
                              - C2LOG * (float)dmin - dl;
            if (bound > SKIP_BOUND) mask |= (1u << t);
        }
    }

    const int strow = tid >> 3, stc8 = (tid & 7) * 8;
    bf16x8 kr0, kr1, vr0, vr1;
    float ldr = 0.f;
    auto prefetch = [&](int k0) {
        kr0 = *(const bf16x8*)(K + base + (size_t)(k0 + strow) * DK + stc8);
        kr1 = *(const bf16x8*)(K + base + (size_t)(k0 + 32 + strow) * DK + stc8);
        vr0 = *(const bf16x8*)(Vt + base + (size_t)strow * LL + k0 + stc8);
        vr1 = *(const bf16x8*)(Vt + base + (size_t)(32 + strow) * LL + k0 + stc8);
        if (tid < 64) ldr = logd2[b * LL + k0 + tid];
    };

    float m_c = -1e30f, l_c = 0.f;
    f32x4 o[4] = {};
    const float dfq = (float)(q - quad * 4);

    int t = (int)__builtin_ctz(mask);   // mask != 0 guaranteed (diagonal)
    prefetch(t * 64);
    for (;;) {
        const unsigned rem = (t < 31) ? (mask >> (t + 1)) : 0u;
        const int tn = rem ? (t + 1 + (int)__builtin_ctz(rem)) : -1;
        __syncthreads();
        *(bf16x8*)&Ks[strow][stc8]       = kr0;
        *(bf16x8*)&Ks[32 + strow][stc8]  = kr1;
        *(bf16x8*)&Vts[strow][stc8]      = vr0;
        *(bf16x8*)&Vts[32 + strow][stc8] = vr1;
        if (tid < 64) logds[tid] = ldr;
        __syncthreads();
        if (tn >= 0) prefetch(tn * 64);
        const int k0 = t * 64;

        f32x4 s[4] = {};
#pragma unroll
        for (int kc = 0; kc < 2; ++kc) {
#pragma unroll
            for (int kt = 0; kt < 4; ++kt) {
                bf16x8 kb = *(const bf16x8*)&Ks[kt * 16 + n16][kc * 32 + quad * 8];
                s[kt] = mfma16(kb, qa[kc], s[kt]);
            }
        }
        const float df = dfq - (float)k0;
#pragma unroll
        for (int kt = 0; kt < 4; ++kt) {
            f32x4 ldv = *(const f32x4*)&logds[kt * 16 + quad * 4];
#pragma unroll
            for (int r = 0; r < 4; ++r)
                s[kt][r] += ldv[r] - C2LOG * fabsf(df - (float)(kt * 16 + r));
        }
        f32x4 mx;
#pragma unroll
        for (int r = 0; r < 4; ++r)
            mx[r] = fmaxf(fmaxf(s[0][r], s[1][r]), fmaxf(s[2][r], s[3][r]));
        float rm = fmaxf(fmaxf(mx[0], mx[1]), fmaxf(mx[2], mx[3]));
        rm = fmaxf(rm, __shfl_xor(rm, 16));
        rm = fmaxf(rm, __shfl_xor(rm, 32));
        const float mn = fmaxf(m_c, rm);
        const float alpha = exp2f_fast(m_c - mn);
        if (__any(mn > m_c)) {
#pragma unroll
            for (int dt = 0; dt < 4; ++dt)
#pragma unroll
                for (int r = 0; r < 4; ++r) o[dt][r] *= alpha;
        }
        f32x4 ps = {0.f, 0.f, 0.f, 0.f};
#pragma unroll
        for (int kt = 0; kt < 4; ++kt)
#pragma unroll
            for (int r = 0; r < 4; ++r) {
                float p = exp2f_fast(s[kt][r] - mn);
                s[kt][r] = p;
                ps[r] += p;
            }
        float psum = (ps[0] + ps[1]) + (ps[2] + ps[3]);
        psum += __shfl_xor(psum, 16);
        psum += __shfl_xor(psum, 32);
        l_c = l_c * alpha + psum;
        m_c = mn;
#pragma unroll
        for (int kt = 0; kt < 4; ++kt) {
            bf16x4 pk;
#pragma unroll
            for (int r = 0; r < 4; ++r) pk[r] = (bf16_t)s[kt][r];
            *(bf16x4*)&Ps[w][n16][kt * 16 + quad * 4] = pk;
        }
        __threadfence_block();
#pragma unroll
        for (int kc = 0; kc < 2; ++kc) {
            bf16x8 pa = *(const bf16x8*)&Ps[w][n16][kc * 32 + quad * 8];
#pragma unroll
            for (int dt = 0; dt < 4; ++dt) {
                bf16x8 vb = *(const bf16x8*)&Vts[dt * 16 + n16][kc * 32 + quad * 8];
                o[dt] = mfma16(vb, pa, o[dt]);
            }
        }
        if (tn < 0) break;
        t = tn;
    }
    const float inv = 1.f / l_c;
#pragma unroll
    for (int dt = 0; dt < 4; ++dt) {
        bf16x4 ov;
#pragma unroll
        for (int r = 0; r < 4; ++r) ov[r] = (bf16_t)(o[dt][r] * inv);
        *(bf16x4*)(ctx + ((size_t)b * LL + q) * DMODEL + h * DK +
                   dt * 16 + quad * 4) = ov;
    }
    float mlv = m_c + log2f_fast(l_c);
    if (quad == 0)
        mlout[(size_t)bh * LL + q] = mlv;
    // block-min of ml over the 64 q rows -> mlmin64[bh][qt]
    mlv = fminf(mlv, __shfl_xor(mlv, 1));
    mlv = fminf(mlv, __shfl_xor(mlv, 2));
    mlv = fminf(mlv, __shfl_xor(mlv, 4));
    mlv = fminf(mlv, __shfl_xor(mlv, 8));
    if (lane == 0) wvmin[w] = mlv;
    __syncthreads();
    if (tid == 0)
        mlmin64[bh * 32 + qt] = fminf(fminf(wvmin[0], wvmin[1]),
                                      fminf(wvmin[2], wvmin[3]));
}

// ---------------------------------------------------------------------------
// fused tail (R4-verified form — best of 4 measured tail structures, 49.5us):
// blocks [0,512): output-projection GEMM (64x128 tile);
// blocks [512,1536): attn.mean(heads), K staged in LDS, per-head loop with
// double-buffer + prefetch. LDS is a UNION of the two branches' buffers.
// mlmin64 (from flash) replaces the old mlstat pass: 128-row supertile bound
// = min of the two 64-row entries (identical tightness).
// ---------------------------------------------------------------------------
__global__ __launch_bounds__(256, 3) void tail_fused_k(
    const bf16_t* __restrict__ A, const bf16_t* __restrict__ Bt,
    const float* __restrict__ b0, float* __restrict__ outf,
    const bf16_t* __restrict__ Q, const bf16_t* __restrict__ K,
    const float* __restrict__ logd2, const float* __restrict__ mlws,
    const float* __restrict__ Qn, const float* __restrict__ Kn,
    const float* __restrict__ ml64, const float* __restrict__ ldx,
    float* __restrict__ outmean)
{
    // union layout: gemm branch: Asw[64*64]bf16 (8192 B) + Bsw[128*64]bf16
    // (16384 B) = 24576 B. mean branch: Ks[2][64][72]bf16 (18432 B) +
    // mls[2][128]f32 (1024 B) + logds[64]f32 (256 B) = 19712 B.
    __shared__ __align__(16) char smem[24576];

    const int bid = blockIdx.x;
    const int tid = threadIdx.x;
    const int lane = tid & 63, w = tid >> 6;
    const int quad = lane >> 4, n16 = lane & 15;

    if (bid < 512) {
        // ---------------- output projection GEMM (verified gemm_out_k body)
        bf16_t* Asw = (bf16_t*)smem;
        bf16_t* Bsw = (bf16_t*)(smem + 8192);
        const int wm = (w & 1) * 32, wn = (w >> 1) * 64;
        const int m0 = (bid >> 3) * 64, n0 = (bid & 7) * 128;
        const int srow = lane >> 3;
        const int scb  = (lane & 7) ^ srow;

        f32x4 acc[2][4] = {};

        for (int K0 = 0; K0 < DMODEL; K0 += 64) {
            __syncthreads();
#pragma unroll
            for (int i = 0; i < 2; ++i) {
                int rb = w * 16 + i * 8;
                gl_lds16(A + (size_t)(m0 + rb + srow) * DMODEL + K0 + scb * 8,
                         &Asw[rb * 64]);
            }
#pragma unroll
            for (int i = 0; i < 4; ++i) {
                int rb = w * 32 + i * 8;
                gl_lds16(Bt + (size_t)(n0 + rb + srow) * DMODEL + K0 + scb * 8,
                         &Bsw[rb * 64]);
            }
            __syncthreads();
#pragma unroll
            for (int kc = 0; kc < 2; ++kc) {
                const int pcb = ((kc * 4 + quad) ^ (n16 & 7)) * 8;
                bf16x8 af[2], bfv[4];
#pragma unroll
                for (int mi = 0; mi < 2; ++mi)
                    af[mi] = *(const bf16x8*)&Asw[(wm + mi * 16 + n16) * 64 + pcb];
#pragma unroll
                for (int ni = 0; ni < 4; ++ni)
                    bfv[ni] = *(const bf16x8*)&Bsw[(wn + ni * 16 + n16) * 64 + pcb];
#pragma unroll
                for (int mi = 0; mi < 2; ++mi)
#pragma unroll
                    for (int ni = 0; ni < 4; ++ni)
                        acc[mi][ni] = mfma16(af[mi], bfv[ni], acc[mi][ni]);
            }
        }
#pragma unroll
        for (int mi = 0; mi < 2; ++mi) {
#pragma unroll
            for (int r = 0; r < 4; ++r) {
                const int m = m0 + wm + mi * 16 + quad * 4 + r;
#pragma unroll
                for (int ni = 0; ni < 4; ++ni) {
                    const int n = n0 + wn + ni * 16 + n16;
                    outf[(size_t)m * DMODEL + n] = acc[mi][ni][r] + b0[n];
                }
            }
        }
        return;
    }

    // ---------------- attn.mean(heads) (R4-verified staged body)
    typedef bf16_t KsRow[64][72];
    KsRow* Ks = (KsRow*)smem;                          // Ks[2][64][72]
    float (*mls)[128] = (float(*)[128])(smem + 18432); // mls[2][128]
    float* logds = (float*)(smem + 19456);             // logds[64]

    const int tb = bid - 512;
    const int k0 = (tb & 31) * 64, q0 = ((tb >> 5) & 15) * 128, b = tb >> 9;
    const int qq[2] = {q0 + w * 32 + n16, q0 + w * 32 + 16 + n16};

    if (tid < 64) logds[tid] = logd2[b * LL + k0 + tid];
    __syncthreads();

    float bias0[2][4][4];
#pragma unroll
    for (int qg = 0; qg < 2; ++qg) {
        const float df = (float)(qq[qg] - k0 - quad * 4);
#pragma unroll
        for (int kt = 0; kt < 4; ++kt) {
            f32x4 ldv = *(const f32x4*)&logds[kt * 16 + quad * 4];
#pragma unroll
            for (int r = 0; r < 4; ++r)
                bias0[qg][kt][r] = ldv[r] - C2LOG * fabsf(df - (float)(kt * 16 + r));
        }
    }

    const int ktl = k0 >> 6, qt64 = q0 >> 6;
    const int dmin = (k0 > q0 + 127) ? (k0 - (q0 + 127))
                   : ((q0 > k0 + 63) ? (q0 - (k0 + 63)) : 0);
    unsigned hmask = 0;
    {
        const float dterm = ldx[b * 32 + ktl] - C2LOG * (float)dmin;
        const int qt = q0 >> 7;
        for (int h = 0; h < NHEAD; ++h) {
            const int bh = b * 16 + h;
            const float mlmin128 = fminf(ml64[bh * 32 + qt64],
                                         ml64[bh * 32 + qt64 + 1]);
            const float bound = Qn[bh * 16 + qt] * Kn[bh * 32 + ktl] + dterm
                              - mlmin128;
            if (bound > SKIP_BOUND) hmask |= (1u << h);
        }
    }

    f32x4 acc[2][4] = {};

    if (hmask) {
        const int strow = tid >> 3, stc8 = (tid & 7) * 8;
        bf16x8 kr0, kr1, qan[2][2];
        float mlv = 0.f;
        auto load_head = [&](int h) {
            const size_t hb = (size_t)(b * NHEAD + h) * LL * DK;
            kr0 = *(const bf16x8*)(K + hb + (size_t)(k0 + strow) * DK + stc8);
            kr1 = *(const bf16x8*)(K + hb + (size_t)(k0 + 32 + strow) * DK + stc8);
#pragma unroll
            for (int qg = 0; qg < 2; ++qg)
#pragma unroll
                for (int kc = 0; kc < 2; ++kc)
                    qan[qg][kc] = *(const bf16x8*)(Q + hb + (size_t)qq[qg] * DK +
                                                   kc * 32 + quad * 8);
            if (tid < 128) mlv = mlws[(size_t)(b * NHEAD + h) * LL + q0 + tid];
        };

        int h = (int)__builtin_ctz(hmask);
        load_head(h);
        int pc = 0;
        for (;;) {
            const unsigned rem = (h < 15) ? (hmask >> (h + 1)) : 0u;
            const int hn = rem ? (h + 1 + (int)__builtin_ctz(rem)) : -1;
            const int p = pc & 1;
            *(bf16x8*)&Ks[p][strow][stc8]      = kr0;
            *(bf16x8*)&Ks[p][32 + strow][stc8] = kr1;
            if (tid < 128) mls[p][tid] = mlv;
            bf16x8 qc[2][2] = {{qan[0][0], qan[0][1]}, {qan[1][0], qan[1][1]}};
            __syncthreads();
            if (hn >= 0) load_head(hn);

            f32x4 s[2][4] = {};
#pragma unroll
            for (int kc = 0; kc < 2; ++kc) {
#pragma unroll
                for (int kt = 0; kt < 4; ++kt) {
                    bf16x8 kb = *(const bf16x8*)&Ks[p][kt * 16 + n16][kc * 32 + quad * 8];
                    s[0][kt] = mfma16(kb, qc[0][kc], s[0][kt]);
                    s[1][kt] = mfma16(kb, qc[1][kc], s[1][kt]);
                }
            }
#pragma unroll
            for (int qg = 0; qg < 2; ++qg) {
                const float ml = mls[p][w * 32 + qg * 16 + n16];
#pragma unroll
                for (int kt = 0; kt < 4; ++kt)
#pragma unroll
                    for (int r = 0; r < 4; ++r)
                        acc[qg][kt][r] += exp2f_fast(s[qg][kt][r] +
                                                     bias0[qg][kt][r] - ml);
            }
            ++pc;
            if (hn < 0) break;
            h = hn;
        }
    }

    const float invH = 1.f / (float)NHEAD;
#pragma unroll
    for (int qg = 0; qg < 2; ++qg)
#pragma unroll
        for (int kt = 0; kt < 4; ++kt) {
            f32x4 ov;
#pragma unroll
            for (int r = 0; r < 4; ++r) ov[r] = acc[qg][kt][r] * invH;
            *(f32x4*)(outmean + ((size_t)b * LL + qq[qg]) * LL + k0 +
                      kt * 16 + quad * 4) = ov;
        }
}

// ---------------------------------------------------------------------------
extern "C" void kernel_launch(void* const* d_in, const int* in_sizes, int n_in,
                              void* d_out, int out_size, void* d_ws, size_t ws_size,
                              hipStream_t stream) {
    const float* x  = (const float*)d_in[0];
    const float* dr = (const float*)d_in[1];
    const float* Wq = (const float*)d_in[2];
    const float* bq = (const float*)d_in[3];
    const float* Wk = (const float*)d_in[4];
    const float* bk = (const float*)d_in[5];
    const float* Wv = (const float*)d_in[6];
    const float* bv = (const float*)d_in[7];
    const float* Wo = (const float*)d_in[8];
    const float* bo = (const float*)d_in[9];
    float* out = (float*)d_out;
    char* ws = (char*)d_ws;
    const size_t MB = 1ull << 20;

    bf16_t* xb   = (bf16_t*)(ws);             // 8 MB; reused as ctx after QKV gemm
    bf16_t* Wcat = (bf16_t*)(ws + 8 * MB);    // 6 MB  [3072][1024]
    bf16_t* Wot  = (bf16_t*)(ws + 14 * MB);   // 2 MB
    bf16_t* Qb   = (bf16_t*)(ws + 16 * MB);   // 8 MB
    bf16_t* Kb   = (bf16_t*)(ws + 24 * MB);   // 8 MB
    bf16_t* Vtb  = (bf16_t*)(ws + 32 * MB);   // 8 MB  [b,h,dk,l]
    float*  logd = (float*)(ws + 40 * MB);    // 16 KB
    float*  mlws = (float*)(ws + 41 * MB);    // 256 KB
    float*  Qns  = (float*)(ws + 42 * MB);            // [32][16]
    float*  Kns  = (float*)(ws + 42 * MB + 4096);     // [32][32]
    float*  dlb  = (float*)(ws + 42 * MB + 12288);    // [32][16]
    float*  ldxp = (float*)(ws + 42 * MB + 16384);    // [2][32]
    float*  ml64 = (float*)(ws + 42 * MB + 20480);    // [32][32]
    bf16_t* ctx  = xb;

    prep_fused_k<<<3072, 256, 0, stream>>>(x, dr, xb, logd,
                                           Wq, Wk, Wv, Wo, Wcat, Wot);

    gemm128_k<<<dim3(24, 32), 256, 0, stream>>>(xb, Wcat, bq, bk, bv, dr,
                                                Qb, Kb, Vtb);
    stats_k<<<256, 256, 0, stream>>>(Qb, Kb, logd, Qns, Kns, dlb, ldxp);

    attn_flash_mfma_k<<<dim3(32, 32), 256, 0, stream>>>(Qb, Kb, Vtb, logd,
                                                        Qns, Kns, dlb, ldxp,
                                                        ctx, mlws, ml64);
    tail_fused_k<<<1536, 256, 0, stream>>>(ctx, Wot, bo, out,
                                           Qb, Kb, logd, mlws, Qns, Kns,
                                           ml64, ldxp,
                                           out + (size_t)MTOT * DMODEL);
}

// Round 9
// 208.767 us; speedup vs baseline: 1.4251x; 1.0247x over previous
//
#include <hip/hip_runtime.h>
#include <math.h>

#define DMODEL 1024
#define NHEAD  16
#define DK     64
#define BB     2
#define LL     2048
#define MTOT   (BB*LL)   // 4096

#define LOG2E      1.4426950408889634f
#define SCQ        (0.125f * LOG2E)    // folded into Q at projection epilogue
#define C2LOG      (0.1f * LOG2E)      // distance coeff in log2 domain
#define SKIP_BOUND (-24.0f)            // skip tile if max log2(P) below this

typedef __bf16 bf16_t;
typedef __bf16 bf16x8 __attribute__((ext_vector_type(8)));
typedef __bf16 bf16x4 __attribute__((ext_vector_type(4)));
typedef float  f32x4  __attribute__((ext_vector_type(4)));

static __device__ __forceinline__ f32x4 mfma16(bf16x8 a, bf16x8 b, f32x4 c) {
    return __builtin_amdgcn_mfma_f32_16x16x32_bf16(a, b, c, 0, 0, 0);
}
static __device__ __forceinline__ float exp2f_fast(float x) {
    return __builtin_amdgcn_exp2f(x);
}
static __device__ __forceinline__ float log2f_fast(float x) {
    return __builtin_amdgcn_logf(x);
}
static __device__ __forceinline__ void gl_lds16(const bf16_t* g, bf16_t* l) {
    __builtin_amdgcn_global_load_lds(
        (const __attribute__((address_space(1))) unsigned int*)g,
        (__attribute__((address_space(3))) unsigned int*)l, 16, 0, 0);
}

// ---------------------------------------------------------------------------
// fused prep: blocks [0,2048): x -> bf16 (+ logd2); blocks [2048,3072):
// W[k][n] f32 -> Wt[n][k] bf16 (transpose + convert), 4 matrices.
// ---------------------------------------------------------------------------
__global__ __launch_bounds__(256) void prep_fused_k(
    const float* __restrict__ x, const float* __restrict__ dr,
    bf16_t* __restrict__ xb, float* __restrict__ logd2,
    const float* __restrict__ Wq, const float* __restrict__ Wk,
    const float* __restrict__ Wv, const float* __restrict__ Wo,
    bf16_t* __restrict__ Wcat, bf16_t* __restrict__ Wot)
{
    __shared__ __align__(16) float Ts[64][68];
    const int bid = blockIdx.x;
    const int tid = threadIdx.x;
    if (bid < 2048) {
        size_t gid = (size_t)bid * 256 + tid;   // 524288 total
        size_t off = gid * 8;
        float4 a = *(const float4*)(x + off);
        float4 c = *(const float4*)(x + off + 4);
        float va[8] = {a.x, a.y, a.z, a.w, c.x, c.y, c.z, c.w};
        bf16x8 o1;
#pragma unroll
        for (int j = 0; j < 8; ++j) o1[j] = (bf16_t)va[j];
        *(bf16x8*)(xb + off) = o1;
        if (gid < MTOT) logd2[gid] = log2f_fast(dr[gid] + 1e-6f);
    } else {
        const int t = bid - 2048;
        const int z = t >> 8;
        const float* W = (z == 0) ? Wq : (z == 1) ? Wk : (z == 2) ? Wv : Wo;
        bf16_t* dst = (z < 3) ? (Wcat + (size_t)z * DMODEL * DMODEL) : Wot;
        const int k0 = (t & 15) * 64, n0 = ((t >> 4) & 15) * 64;
#pragma unroll
        for (int i = 0; i < 4; ++i) {
            int u = tid + 256 * i, r = u >> 4, c4 = (u & 15) * 4;
            *(float4*)&Ts[r][c4] = *(const float4*)(W + (size_t)(k0 + r) * DMODEL + n0 + c4);
        }
        __syncthreads();
#pragma unroll
        for (int i = 0; i < 2; ++i) {
            int u = tid + 256 * i, n = u >> 3, k8 = (u & 7) * 8;
            bf16x8 v;
#pragma unroll
            for (int j = 0; j < 8; ++j) v[j] = (bf16_t)Ts[k8 + j][n];
            *(bf16x8*)(dst + (size_t)(n0 + n) * DMODEL + k0 + k8) = v;
        }
    }
}

// ---------------------------------------------------------------------------
// 128x128 MFMA GEMM, BK=64, global_load_lds + XOR-swizzled LDS.
// QKV epilogue (Q prescaled SCQ; V written transposed+scaled).
// ---------------------------------------------------------------------------
__global__ __launch_bounds__(256, 3) void gemm128_k(
    const bf16_t* __restrict__ A, const bf16_t* __restrict__ Bt,
    const float* __restrict__ b0, const float* __restrict__ b1,
    const float* __restrict__ b2, const float* __restrict__ delta,
    bf16_t* __restrict__ outQ, bf16_t* __restrict__ outK,
    bf16_t* __restrict__ outVt)
{
    __shared__ __align__(16) bf16_t Asw[128 * 64];
    __shared__ __align__(16) bf16_t Bsw[128 * 64];
    const int tid = threadIdx.x, lane = tid & 63, w = tid >> 6;
    const int quad = lane >> 4, n16 = lane & 15;
    const int wm = (w & 1) * 64, wn = (w >> 1) * 64;
    const int m0 = blockIdx.y * 128, n0 = blockIdx.x * 128;
    const int srow = lane >> 3;
    const int scb  = (lane & 7) ^ srow;

    f32x4 acc[4][4] = {};

    for (int K0 = 0; K0 < DMODEL; K0 += 64) {
        __syncthreads();
#pragma unroll
        for (int i = 0; i < 4; ++i) {
            int rb = w * 32 + i * 8;
            gl_lds16(A  + (size_t)(m0 + rb + srow) * DMODEL + K0 + scb * 8,
                     &Asw[rb * 64]);
            gl_lds16(Bt + (size_t)(n0 + rb + srow) * DMODEL + K0 + scb * 8,
                     &Bsw[rb * 64]);
        }
        __syncthreads();
#pragma unroll
        for (int kc = 0; kc < 2; ++kc) {
            const int pcb = ((kc * 4 + quad) ^ (n16 & 7)) * 8;
            bf16x8 af[4], bfv[4];
#pragma unroll
            for (int mi = 0; mi < 4; ++mi)
                af[mi] = *(const bf16x8*)&Asw[(wm + mi * 16 + n16) * 64 + pcb];
#pragma unroll
            for (int ni = 0; ni < 4; ++ni)
                bfv[ni] = *(const bf16x8*)&Bsw[(wn + ni * 16 + n16) * 64 + pcb];
#pragma unroll
            for (int mi = 0; mi < 4; ++mi)
#pragma unroll
                for (int ni = 0; ni < 4; ++ni)
                    acc[mi][ni] = mfma16(af[mi], bfv[ni], acc[mi][ni]);
        }
    }

    const int region = n0 >> 10;
    if (region == 2) {
#pragma unroll
        for (int mi = 0; mi < 4; ++mi) {
            const int mbase = m0 + wm + mi * 16 + quad * 4;
            const int bidx = mbase >> 11, l = mbase & (LL - 1);
            const f32x4 dm4 = *(const f32x4*)(delta + mbase);
#pragma unroll
            for (int ni = 0; ni < 4; ++ni) {
                const int nl = (n0 & 1023) + wn + ni * 16 + n16;
                const int h = nl >> 6, dd = nl & 63;
                const float bv = b2[nl];
                bf16x4 pk;
#pragma unroll
                for (int r = 0; r < 4; ++r)
                    pk[r] = (bf16_t)(acc[mi][ni][r] * dm4[r] + bv);
                *(bf16x4*)(outVt + ((size_t)(bidx * NHEAD + h) * DK + dd) * LL + l) = pk;
            }
        }
    } else {
        const float* bias = (region == 0) ? b0 : b1;
        bf16_t* dst = (region == 0) ? outQ : outK;
        const float qs = (region == 0) ? SCQ : 1.0f;
#pragma unroll
        for (int mi = 0; mi < 4; ++mi) {
#pragma unroll
            for (int r = 0; r < 4; ++r) {
                const int m = m0 + wm + mi * 16 + quad * 4 + r;
                const int bidx = m >> 11, l = m & (LL - 1);
#pragma unroll
                for (int ni = 0; ni < 4; ++ni) {
                    const int nl = (n0 & 1023) + wn + ni * 16 + n16;
                    const int h = nl >> 6, dd = nl & 63;
                    float v = (acc[mi][ni][r] + bias[nl]) * qs;
                    dst[(((size_t)(bidx * NHEAD + h) * LL) + l) * DK + dd] = (bf16_t)v;
                }
            }
        }
    }
}

// ---------------------------------------------------------------------------
// stats, 256 blocks (8 segments x 256 rows per (b,h)).
// ---------------------------------------------------------------------------
__global__ __launch_bounds__(256) void stats_k(
    const bf16_t* __restrict__ Q, const bf16_t* __restrict__ K,
    const float* __restrict__ logd2, float* __restrict__ Qn,
    float* __restrict__ Kn, float* __restrict__ dlb, float* __restrict__ ldx)
{
    __shared__ float qn_s[256], kn_s[256], dg_s[256];
    const int blk = blockIdx.x;
    const int bh = blk >> 3, seg = blk & 7, b = bh >> 4;
    const int tid = threadIdx.x;
    const int row = seg * 256 + tid;
    const size_t base = (size_t)bh * LL * DK;

    float qn2 = 0.f, kn2 = 0.f, dg = 0.f;
#pragma unroll
    for (int j = 0; j < 8; ++j) {
        bf16x8 qv = *(const bf16x8*)(Q + base + (size_t)row * DK + j * 8);
        bf16x8 kv = *(const bf16x8*)(K + base + (size_t)row * DK + j * 8);
#pragma unroll
        for (int e = 0; e < 8; ++e) {
            float fq = (float)qv[e], fk = (float)kv[e];
            qn2 += fq * fq; kn2 += fk * fk; dg += fq * fk;
        }
    }
    qn_s[tid] = qn2;
    kn_s[tid] = kn2;
    dg_s[tid] = dg + logd2[b * LL + row];
    __syncthreads();

    if (tid < 2) {               // 2 q-tiles of 128 rows in this segment
        float mq = 0.f, md = 1e30f;
        for (int r = 0; r < 128; ++r) {
            mq = fmaxf(mq, qn_s[tid * 128 + r]);
            md = fminf(md, dg_s[tid * 128 + r]);
        }
        Qn[bh * 16 + seg * 2 + tid] = sqrtf(mq);
        dlb[bh * 16 + seg * 2 + tid] = md;
    } else if (tid >= 64 && tid < 68) {   // 4 k-tiles of 64 rows
        const int t = tid - 64;
        float mk = 0.f;
        for (int r = 0; r < 64; ++r) mk = fmaxf(mk, kn_s[t * 64 + r]);
        Kn[bh * 32 + seg * 4 + t] = sqrtf(mk);
    } else if (tid >= 128 && tid < 132 && (bh & 15) == 0) {
        const int t = tid - 128;
        float ml = -1e30f;
        for (int r = 0; r < 64; ++r)
            ml = fmaxf(ml, logd2[b * LL + seg * 256 + t * 64 + r]);
        ldx[b * 32 + seg * 4 + t] = ml;
    }
}

// ---------------------------------------------------------------------------
// MFMA flash attention, S^T form, 64 q/block. ALSO emits mlmin64[bh][qt64] =
// min over the block's 64 q of (m + log2 l) — replaces the mlstat_k launch.
// ---------------------------------------------------------------------------
__global__ __launch_bounds__(256, 4) void attn_flash_mfma_k(
    const bf16_t* __restrict__ Q, const bf16_t* __restrict__ K,
    const bf16_t* __restrict__ Vt, const float* __restrict__ logd2,
    const float* __restrict__ Qn, const float* __restrict__ Kn,
    const float* __restrict__ dlb, const float* __restrict__ ldx,
    bf16_t* __restrict__ ctx, float* __restrict__ mlout,
    float* __restrict__ mlmin64)
{
    __shared__ __align__(16) bf16_t Ks[64][72];
    __shared__ __align__(16) bf16_t Vts[64][72];
    __shared__ __align__(16) bf16_t Ps[4][16][72];
    __shared__ float logds[64];
    __shared__ float wvmin[4];

    const int tid = threadIdx.x;
    const int lane = tid & 63, w = tid >> 6;
    const int quad = lane >> 4, n16 = lane & 15;
    const int bh = blockIdx.x, b = bh >> 4, h = bh & 15;
    const int qt = blockIdx.y, q0 = qt * 64;
    const size_t base = (size_t)bh * LL * DK;
    const int q = q0 + w * 16 + n16;

    bf16x8 qa[2];
#pragma unroll
    for (int kc = 0; kc < 2; ++kc)
        qa[kc] = *(const bf16x8*)(Q + base + (size_t)q * DK + kc * 32 + quad * 8);

    // active-tile mask (block-uniform); stats are per 128-q supertile
    unsigned mask = 0;
    {
        const float qn = Qn[bh * 16 + (qt >> 1)], dl = dlb[bh * 16 + (qt >> 1)];
        for (int t = 0; t < 32; ++t) {
            const int kc0 = t * 64;
            const int dmin = (kc0 > q0 + 63) ? (kc0 - (q0 + 63))
                           : ((q0 > kc0 + 63) ? (q0 - (kc0 + 63)) : 0);
            const float bound = qn * Kn[bh * 32 + t] + ldx[b * 32 + t]
                              - C2LOG * (float)dmin - dl;
            if (bound > SKIP_BOUND) mask |= (1u << t);
        }
    }

    const int strow = tid >> 3, stc8 = (tid & 7) * 8;
    bf16x8 kr0, kr1, vr0, vr1;
    float ldr = 0.f;
    auto prefetch = [&](int k0) {
        kr0 = *(const bf16x8*)(K + base + (size_t)(k0 + strow) * DK + stc8);
        kr1 = *(const bf16x8*)(K + base + (size_t)(k0 + 32 + strow) * DK + stc8);
        vr0 = *(const bf16x8*)(Vt + base + (size_t)strow * LL + k0 + stc8);
        vr1 = *(const bf16x8*)(Vt + base + (size_t)(32 + strow) * LL + k0 + stc8);
        if (tid < 64) ldr = logd2[b * LL + k0 + tid];
    };

    float m_c = -1e30f, l_c = 0.f;
    f32x4 o[4] = {};
    const float dfq = (float)(q - quad * 4);

    int t = (int)__builtin_ctz(mask);   // mask != 0 guaranteed (diagonal)
    prefetch(t * 64);
    for (;;) {
        const unsigned rem = (t < 31) ? (mask >> (t + 1)) : 0u;
        const int tn = rem ? (t + 1 + (int)__builtin_ctz(rem)) : -1;
        __syncthreads();
        *(bf16x8*)&Ks[strow][stc8]       = kr0;
        *(bf16x8*)&Ks[32 + strow][stc8]  = kr1;
        *(bf16x8*)&Vts[strow][stc8]      = vr0;
        *(bf16x8*)&Vts[32 + strow][stc8] = vr1;
        if (tid < 64) logds[tid] = ldr;
        __syncthreads();
        if (tn >= 0) prefetch(tn * 64);
        const int k0 = t * 64;

        f32x4 s[4] = {};
#pragma unroll
        for (int kc = 0; kc < 2; ++kc) {
#pragma unroll
            for (int kt = 0; kt < 4; ++kt) {
                bf16x8 kb = *(const bf16x8*)&Ks[kt * 16 + n16][kc * 32 + quad * 8];
                s[kt] = mfma16(kb, qa[kc], s[kt]);
            }
        }
        const float df = dfq - (float)k0;
#pragma unroll
        for (int kt = 0; kt < 4; ++kt) {
            f32x4 ldv = *(const f32x4*)&logds[kt * 16 + quad * 4];
#pragma unroll
            for (int r = 0; r < 4; ++r)
                s[kt][r] += ldv[r] - C2LOG * fabsf(df - (float)(kt * 16 + r));
        }
        f32x4 mx;
#pragma unroll
        for (int r = 0; r < 4; ++r)
            mx[r] = fmaxf(fmaxf(s[0][r], s[1][r]), fmaxf(s[2][r], s[3][r]));
        float rm = fmaxf(fmaxf(mx[0], mx[1]), fmaxf(mx[2], mx[3]));
        rm = fmaxf(rm, __shfl_xor(rm, 16));
        rm = fmaxf(rm, __shfl_xor(rm, 32));
        const float mn = fmaxf(m_c, rm);
        const float alpha = exp2f_fast(m_c - mn);
        if (__any(mn > m_c)) {
#pragma unroll
            for (int dt = 0; dt < 4; ++dt)
#pragma unroll
                for (int r = 0; r < 4; ++r) o[dt][r] *= alpha;
        }
        f32x4 ps = {0.f, 0.f, 0.f, 0.f};
#pragma unroll
        for (int kt = 0; kt < 4; ++kt)
#pragma unroll
            for (int r = 0; r < 4; ++r) {
                float p = exp2f_fast(s[kt][r] - mn);
                s[kt][r] = p;
                ps[r] += p;
            }
        float psum = (ps[0] + ps[1]) + (ps[2] + ps[3]);
        psum += __shfl_xor(psum, 16);
        psum += __shfl_xor(psum, 32);
        l_c = l_c * alpha + psum;
        m_c = mn;
#pragma unroll
        for (int kt = 0; kt < 4; ++kt) {
            bf16x4 pk;
#pragma unroll
            for (int r = 0; r < 4; ++r) pk[r] = (bf16_t)s[kt][r];
            *(bf16x4*)&Ps[w][n16][kt * 16 + quad * 4] = pk;
        }
        __threadfence_block();
#pragma unroll
        for (int kc = 0; kc < 2; ++kc) {
            bf16x8 pa = *(const bf16x8*)&Ps[w][n16][kc * 32 + quad * 8];
#pragma unroll
            for (int dt = 0; dt < 4; ++dt) {
                bf16x8 vb = *(const bf16x8*)&Vts[dt * 16 + n16][kc * 32 + quad * 8];
                o[dt] = mfma16(vb, pa, o[dt]);
            }
        }
        if (tn < 0) break;
        t = tn;
    }
    const float inv = 1.f / l_c;
#pragma unroll
    for (int dt = 0; dt < 4; ++dt) {
        bf16x4 ov;
#pragma unroll
        for (int r = 0; r < 4; ++r) ov[r] = (bf16_t)(o[dt][r] * inv);
        *(bf16x4*)(ctx + ((size_t)b * LL + q) * DMODEL + h * DK +
                   dt * 16 + quad * 4) = ov;
    }
    float mlv = m_c + log2f_fast(l_c);
    if (quad == 0)
        mlout[(size_t)bh * LL + q] = mlv;
    // block-min of ml over the 64 q rows -> mlmin64[bh][qt]
    mlv = fminf(mlv, __shfl_xor(mlv, 1));
    mlv = fminf(mlv, __shfl_xor(mlv, 2));
    mlv = fminf(mlv, __shfl_xor(mlv, 4));
    mlv = fminf(mlv, __shfl_xor(mlv, 8));
    if (lane == 0) wvmin[w] = mlv;
    __syncthreads();
    if (tid == 0)
        mlmin64[bh * 32 + qt] = fminf(fminf(wvmin[0], wvmin[1]),
                                      fminf(wvmin[2], wvmin[3]));
}

// ---------------------------------------------------------------------------
// fused tail. blocks [0,2048): attn.mean at 64q x 64k grain (was 128x64):
// ~600 half-size heavy blocks spread evenly over 256 CUs (R8 diagnosis:
// tail time = heavy-block internals + imbalance, NOT residency — R2 vs R4
// LDS halving and R7 occupancy boost were both null). 64-row grain also
// uses ml64 directly (tighter mlmin -> more head-skips) and tighter dmin.
// Block order rank-major diagonal-first. Same staged per-head body as R4/R8.
// blocks [2048,2560): output-projection GEMM (verified gemm_out_k body).
// ---------------------------------------------------------------------------
__global__ __launch_bounds__(256, 3) void tail_fused_k(
    const bf16_t* __restrict__ A, const bf16_t* __restrict__ Bt,
    const float* __restrict__ b0, float* __restrict__ outf,
    const bf16_t* __restrict__ Q, const bf16_t* __restrict__ K,
    const float* __restrict__ logd2, const float* __restrict__ mlws,
    const float* __restrict__ Qn, const float* __restrict__ Kn,
    const float* __restrict__ ml64, const float* __restrict__ ldx,
    float* __restrict__ outmean)
{
    // union layout: gemm branch: Asw[64*64]bf16 (8192 B) + Bsw[128*64]bf16
    // (16384 B) = 24576 B. mean branch: Ks[2][64][72]bf16 (18432 B) +
    // mls[2][64]f32 (512 B) + logds[64]f32 (256 B) = 19200 B.
    __shared__ __align__(16) char smem[24576];

    const int bid = blockIdx.x;
    const int tid = threadIdx.x;
    const int lane = tid & 63, w = tid >> 6;
    const int quad = lane >> 4, n16 = lane & 15;

    if (bid >= 2048) {
        // ---------------- output projection GEMM (verified gemm_out_k body)
        bf16_t* Asw = (bf16_t*)smem;
        bf16_t* Bsw = (bf16_t*)(smem + 8192);
        const int gb = bid - 2048;
        const int wm = (w & 1) * 32, wn = (w >> 1) * 64;
        const int m0 = (gb >> 3) * 64, n0 = (gb & 7) * 128;
        const int srow = lane >> 3;
        const int scb  = (lane & 7) ^ srow;

        f32x4 acc[2][4] = {};

        for (int K0 = 0; K0 < DMODEL; K0 += 64) {
            __syncthreads();
#pragma unroll
            for (int i = 0; i < 2; ++i) {
                int rb = w * 16 + i * 8;
                gl_lds16(A + (size_t)(m0 + rb + srow) * DMODEL + K0 + scb * 8,
                         &Asw[rb * 64]);
            }
#pragma unroll
            for (int i = 0; i < 4; ++i) {
                int rb = w * 32 + i * 8;
                gl_lds16(Bt + (size_t)(n0 + rb + srow) * DMODEL + K0 + scb * 8,
                         &Bsw[rb * 64]);
            }
            __syncthreads();
#pragma unroll
            for (int kc = 0; kc < 2; ++kc) {
                const int pcb = ((kc * 4 + quad) ^ (n16 & 7)) * 8;
                bf16x8 af[2], bfv[4];
#pragma unroll
                for (int mi = 0; mi < 2; ++mi)
                    af[mi] = *(const bf16x8*)&Asw[(wm + mi * 16 + n16) * 64 + pcb];
#pragma unroll
                for (int ni = 0; ni < 4; ++ni)
                    bfv[ni] = *(const bf16x8*)&Bsw[(wn + ni * 16 + n16) * 64 + pcb];
#pragma unroll
                for (int mi = 0; mi < 2; ++mi)
#pragma unroll
                    for (int ni = 0; ni < 4; ++ni)
                        acc[mi][ni] = mfma16(af[mi], bfv[ni], acc[mi][ni]);
            }
        }
#pragma unroll
        for (int mi = 0; mi < 2; ++mi) {
#pragma unroll
            for (int r = 0; r < 4; ++r) {
                const int m = m0 + wm + mi * 16 + quad * 4 + r;
#pragma unroll
                for (int ni = 0; ni < 4; ++ni) {
                    const int n = n0 + wn + ni * 16 + n16;
                    outf[(size_t)m * DMODEL + n] = acc[mi][ni][r] + b0[n];
                }
            }
        }
        return;
    }

    // ---------------- attn.mean, 64q x 64k blocks, rank-major decode.
    // bid = rank*64 + (b*32 + q64i): heaviest (rank 0 = diagonal) first.
    const int rank = bid >> 6, bq = bid & 63, b = bq >> 5, q64i = bq & 31;
    const int q0 = q64i * 64;

    int ktile = 0;
    {
        const int c = q64i;              // diagonal k-tile index
        int want = rank;
        for (int d = 0; d < 32; ++d) {
            int ka = c - d;
            if (ka >= 0) {
                if (want == 0) { ktile = ka; break; }
                --want;
            }
            int kb2 = c + d;
            if (d > 0 && kb2 < 32) {
                if (want == 0) { ktile = kb2; break; }
                --want;
            }
        }
    }
    const int k0 = ktile * 64;

    const int qt = q0 >> 7;              // stats supertile (128-row, sound)
    const int qt64 = q0 >> 6;
    const int dmin = (k0 > q0 + 63) ? (k0 - (q0 + 63))
                   : ((q0 > k0 + 63) ? (q0 - (k0 + 63)) : 0);
    unsigned hmask = 0;
    {
        const float dterm = ldx[b * 32 + ktile] - C2LOG * (float)dmin;
        for (int h = 0; h < NHEAD; ++h) {
            const int bh = b * 16 + h;
            const float bound = Qn[bh * 16 + qt] * Kn[bh * 32 + ktile] + dterm
                              - ml64[bh * 32 + qt64];
            if (bound > SKIP_BOUND) hmask |= (1u << h);
        }
    }

    if (!hmask) {
        // write 64x64 zeros: 256 threads x 4 x f32x4
        const int row = tid >> 2, c4 = (tid & 3) * 4;
        const f32x4 z = {0.f, 0.f, 0.f, 0.f};
        float* dst = outmean + ((size_t)b * LL + q0 + row) * LL + k0 + c4;
#pragma unroll
        for (int cc = 0; cc < 4; ++cc)
            *(f32x4*)(dst + cc * 16) = z;
        return;
    }

    typedef bf16_t KsRow[64][72];
    KsRow* Ks = (KsRow*)smem;                          // Ks[2][64][72]
    float (*mls)[64] = (float(*)[64])(smem + 18432);   // mls[2][64]
    float* logds = (float*)(smem + 18944);             // logds[64]

    const int qq = q0 + w * 16 + n16;    // this thread's q-row

    if (tid < 64) logds[tid] = logd2[b * LL + k0 + tid];
    __syncthreads();

    float bias0[4][4];
    {
        const float df = (float)(qq - k0 - quad * 4);
#pragma unroll
        for (int kt = 0; kt < 4; ++kt) {
            f32x4 ldv = *(const f32x4*)&logds[kt * 16 + quad * 4];
#pragma unroll
            for (int r = 0; r < 4; ++r)
                bias0[kt][r] = ldv[r] - C2LOG * fabsf(df - (float)(kt * 16 + r));
        }
    }

    f32x4 acc[4] = {};
    {
        const int strow = tid >> 3, stc8 = (tid & 7) * 8;
        bf16x8 kr0, kr1, qan[2];
        float mlv = 0.f;
        auto load_head = [&](int h) {
            const size_t hb = (size_t)(b * NHEAD + h) * LL * DK;
            kr0 = *(const bf16x8*)(K + hb + (size_t)(k0 + strow) * DK + stc8);
            kr1 = *(const bf16x8*)(K + hb + (size_t)(k0 + 32 + strow) * DK + stc8);
#pragma unroll
            for (int kc = 0; kc < 2; ++kc)
                qan[kc] = *(const bf16x8*)(Q + hb + (size_t)qq * DK +
                                           kc * 32 + quad * 8);
            if (tid < 64) mlv = mlws[(size_t)(b * NHEAD + h) * LL + q0 + tid];
        };

        int h = (int)__builtin_ctz(hmask);
        load_head(h);
        int pc = 0;
        for (;;) {
            const unsigned rem = (h < 15) ? (hmask >> (h + 1)) : 0u;
            const int hn = rem ? (h + 1 + (int)__builtin_ctz(rem)) : -1;
            const int p = pc & 1;
            *(bf16x8*)&Ks[p][strow][stc8]      = kr0;
            *(bf16x8*)&Ks[p][32 + strow][stc8] = kr1;
            if (tid < 64) mls[p][tid] = mlv;
            bf16x8 qc[2] = {qan[0], qan[1]};
            __syncthreads();
            if (hn >= 0) load_head(hn);

            f32x4 s[4] = {};
#pragma unroll
            for (int kc = 0; kc < 2; ++kc) {
#pragma unroll
                for (int kt = 0; kt < 4; ++kt) {
                    bf16x8 kb = *(const bf16x8*)&Ks[p][kt * 16 + n16][kc * 32 + quad * 8];
                    s[kt] = mfma16(kb, qc[kc], s[kt]);
                }
            }
            const float ml = mls[p][w * 16 + n16];
#pragma unroll
            for (int kt = 0; kt < 4; ++kt)
#pragma unroll
                for (int r = 0; r < 4; ++r)
                    acc[kt][r] += exp2f_fast(s[kt][r] + bias0[kt][r] - ml);
            ++pc;
            if (hn < 0) break;
            h = hn;
        }
    }

    const float invH = 1.f / (float)NHEAD;
#pragma unroll
    for (int kt = 0; kt < 4; ++kt) {
        f32x4 ov;
#pragma unroll
        for (int r = 0; r < 4; ++r) ov[r] = acc[kt][r] * invH;
        *(f32x4*)(outmean + ((size_t)b * LL + qq) * LL + k0 +
                  kt * 16 + quad * 4) = ov;
    }
}

// ---------------------------------------------------------------------------
extern "C" void kernel_launch(void* const* d_in, const int* in_sizes, int n_in,
                              void* d_out, int out_size, void* d_ws, size_t ws_size,
                              hipStream_t stream) {
    const float* x  = (const float*)d_in[0];
    const float* dr = (const float*)d_in[1];
    const float* Wq = (const float*)d_in[2];
    const float* bq = (const float*)d_in[3];
    const float* Wk = (const float*)d_in[4];
    const float* bk = (const float*)d_in[5];
    const float* Wv = (const float*)d_in[6];
    const float* bv = (const float*)d_in[7];
    const float* Wo = (const float*)d_in[8];
    const float* bo = (const float*)d_in[9];
    float* out = (float*)d_out;
    char* ws = (char*)d_ws;
    const size_t MB = 1ull << 20;

    bf16_t* xb   = (bf16_t*)(ws);             // 8 MB; reused as ctx after QKV gemm
    bf16_t* Wcat = (bf16_t*)(ws + 8 * MB);    // 6 MB  [3072][1024]
    bf16_t* Wot  = (bf16_t*)(ws + 14 * MB);   // 2 MB
    bf16_t* Qb   = (bf16_t*)(ws + 16 * MB);   // 8 MB
    bf16_t* Kb   = (bf16_t*)(ws + 24 * MB);   // 8 MB
    bf16_t* Vtb  = (bf16_t*)(ws + 32 * MB);   // 8 MB  [b,h,dk,l]
    float*  logd = (float*)(ws + 40 * MB);    // 16 KB
    float*  mlws = (float*)(ws + 41 * MB);    // 256 KB
    float*  Qns  = (float*)(ws + 42 * MB);            // [32][16]
    float*  Kns  = (float*)(ws + 42 * MB + 4096);     // [32][32]
    float*  dlb  = (float*)(ws + 42 * MB + 12288);    // [32][16]
    float*  ldxp = (float*)(ws + 42 * MB + 16384);    // [2][32]
    float*  ml64 = (float*)(ws + 42 * MB + 20480);    // [32][32]
    bf16_t* ctx  = xb;

    prep_fused_k<<<3072, 256, 0, stream>>>(x, dr, xb, logd,
                                           Wq, Wk, Wv, Wo, Wcat, Wot);

    gemm128_k<<<dim3(24, 32), 256, 0, stream>>>(xb, Wcat, bq, bk, bv, dr,
                                                Qb, Kb, Vtb);
    stats_k<<<256, 256, 0, stream>>>(Qb, Kb, logd, Qns, Kns, dlb, ldxp);

    attn_flash_mfma_k<<<dim3(32, 32), 256, 0, stream>>>(Qb, Kb, Vtb, logd,
                                                        Qns, Kns, dlb, ldxp,
                                                        ctx, mlws, ml64);
    tail_fused_k<<<2560, 256, 0, stream>>>(ctx, Wot, bo, out,
                                           Qb, Kb, logd, mlws, Qns, Kns,
                                           ml64, ldxp,
                                           out + (size_t)MTOT * DMODEL);
}